// Round 9
// baseline (525.499 us; speedup 1.0000x reference)
//
#include <hip/hip_runtime.h>
#include <math.h>

#define NB 4
#define NSEQ 4096
#define DM 1024
#define NHEAD 16
#define DHD 64
#define MF 256
#define ROWS 16384

#define DN 0.35355339059327373f
#define RATIO 0.0625f
#define HALF_DN2 0.0625f
#define EPSF 1.0e-4f
#define THR_DEFER 4.0f

typedef __attribute__((ext_vector_type(4))) float f32x4;
typedef __attribute__((ext_vector_type(8))) short short8;
typedef __attribute__((ext_vector_type(4))) short short4v;
typedef __attribute__((ext_vector_type(8))) __bf16 bf16x8;
typedef unsigned short ushort_t;

__device__ __forceinline__ unsigned short f2bf(float f) {
  unsigned int u = __builtin_bit_cast(unsigned int, f);
  u += 0x7FFFu + ((u >> 16) & 1u);
  return (unsigned short)(u >> 16);
}
__device__ __forceinline__ float bf2f(unsigned short h) {
  unsigned int u = ((unsigned int)h) << 16;
  return __builtin_bit_cast(float, u);
}

__device__ __forceinline__ f32x4 mfma16(short8 a, short8 b, f32x4 c) {
  return __builtin_amdgcn_mfma_f32_16x16x32_bf16(
      __builtin_bit_cast(bf16x8, a), __builtin_bit_cast(bf16x8, b), c, 0, 0, 0);
}

// 16x16x16 bf16 MFMA (K=16). Fragment mappings validated end-to-end in r4/r5.
__device__ __forceinline__ f32x4 mfma16x16(short4v a, short4v b, f32x4 c) {
#if __has_builtin(__builtin_amdgcn_mfma_f32_16x16x16bf16_1k)
  return __builtin_amdgcn_mfma_f32_16x16x16bf16_1k(a, b, c, 0, 0, 0);
#elif __has_builtin(__builtin_amdgcn_mfma_f32_16x16x16_bf16)
  typedef __attribute__((ext_vector_type(4))) __bf16 bf16x4;
  return __builtin_amdgcn_mfma_f32_16x16x16_bf16(
      __builtin_bit_cast(bf16x4, a), __builtin_bit_cast(bf16x4, b), c, 0, 0, 0);
#else
  asm volatile("s_nop 1\n\t"
               "v_mfma_f32_16x16x16_bf16 %0, %1, %2, %0\n\t"
               "s_nop 7"
               : "+v"(c) : "v"(a), "v"(b));
  return c;
#endif
}

__device__ __forceinline__ void glds16(const void* g, void* l) {
  __builtin_amdgcn_global_load_lds(
      (const __attribute__((address_space(1))) unsigned int*)g,
      (__attribute__((address_space(3))) unsigned int*)l, 16, 0, 0);
}

// ---------------------------------------------------------------------------
// Weight transpose-cast: Wt[n][k] = bf16(W[k][n]).
// ---------------------------------------------------------------------------
__global__ __launch_bounds__(256) void wtrans(const float* __restrict__ W,
                                              ushort_t* __restrict__ Wt)
{
  __shared__ float ts[64][68];
  const int tid = threadIdx.x;
  const int k0 = blockIdx.y * 64, n0 = blockIdx.x * 64;
  const int r = tid >> 4, c4 = (tid & 15) * 4;
  #pragma unroll
  for (int i = 0; i < 4; ++i) {
    float4 v = *(const float4*)&W[(size_t)(k0 + r + i * 16) * DM + n0 + c4];
    *(float4*)&ts[r + i * 16][c4] = v;
  }
  __syncthreads();
  #pragma unroll
  for (int i = 0; i < 4; ++i) {
    const int n = r + i * 16;
    ushort4 o;
    o.x = f2bf(ts[c4 + 0][n]); o.y = f2bf(ts[c4 + 1][n]);
    o.z = f2bf(ts[c4 + 2][n]); o.w = f2bf(ts[c4 + 3][n]);
    *(ushort4*)&Wt[(size_t)(n0 + n) * DM + k0 + c4] = o;
  }
}

// ---------------------------------------------------------------------------
__global__ __launch_bounds__(256) void psplit(const float* __restrict__ P,
                                              ushort_t* __restrict__ PHI,
                                              ushort_t* __restrict__ PLO)
{
  const int i = blockIdx.x * 256 + threadIdx.x;
  const float v = P[i];
  const unsigned short h = f2bf(v);
  PHI[i] = h;
  PLO[i] = f2bf(v - bf2f(h));
}

// ---------------------------------------------------------------------------
__global__ __launch_bounds__(256) void xconv(const float* __restrict__ x,
                                             ushort_t* __restrict__ xb)
{
  const size_t i = ((size_t)blockIdx.x * 256 + threadIdx.x) * 8;
  const float4 a = *(const float4*)&x[i];
  const float4 c = *(const float4*)&x[i + 4];
  short8 o;
  o[0] = f2bf(a.x); o[1] = f2bf(a.y); o[2] = f2bf(a.z); o[3] = f2bf(a.w);
  o[4] = f2bf(c.x); o[5] = f2bf(c.y); o[6] = f2bf(c.z); o[7] = f2bf(c.w);
  *(short8*)&xb[i] = o;
}

// ---------------------------------------------------------------------------
// bf16 MFMA GEMM: C[16384,1024] = A @ Bt^T. 128x128, BK=32. (unchanged)
// EPI: 1=C fp32+bias, 2=VT bf16 [bh][dh][n], 3=hi|lo [row][h][128] + diag.
// ---------------------------------------------------------------------------
template<int EPI>
__global__ __launch_bounds__(256) void gemm_k(const ushort_t* __restrict__ Ab,
                                              const ushort_t* __restrict__ Bt,
                                              const float* __restrict__ bias,
                                              float* __restrict__ C,
                                              ushort_t* __restrict__ VT,
                                              ushort_t* __restrict__ OHL,
                                              float* __restrict__ DIAG)
{
  constexpr int K = DM, N = DM;
  __shared__ ushort_t As[128 * 32];
  __shared__ ushort_t Bs[128 * 32];

  const int tid = threadIdx.x;
  const int l = tid & 63, w = tid >> 6;
  const int ll = l & 15, lh = l >> 4;
  const int wr = w >> 1, wc = w & 1;

  const int bid = blockIdx.x;
  const int swz = (bid & 7) * ((int)gridDim.x >> 3) + (bid >> 3);
  const int bm = swz >> 3, bn = swz & 7;
  const int row0 = bm * 128, col0 = bn * 128;

  const int pb0 = w * 128 + l, pb1 = pb0 + 64;
  const int brow0 = pb0 >> 2, bkq0 = (pb0 & 3) ^ ((brow0 >> 1) & 3);
  const int brow1 = pb1 >> 2, bkq1 = (pb1 & 3) ^ ((brow1 >> 1) & 3);
  const ushort_t* bsrc0 = Bt + (size_t)(col0 + brow0) * K + bkq0 * 8;
  const ushort_t* bsrc1 = Bt + (size_t)(col0 + brow1) * K + bkq1 * 8;
  ushort_t* bdst0 = &Bs[(size_t)(w * 128) * 8];
  ushort_t* bdst1 = &Bs[(size_t)(w * 128 + 64) * 8];

  const ushort_t* asrc0 = Ab + (size_t)(row0 + brow0) * K + bkq0 * 8;
  const ushort_t* asrc1 = Ab + (size_t)(row0 + brow1) * K + bkq1 * 8;

  int aoff[4], boff[4];
  #pragma unroll
  for (int mt = 0; mt < 4; ++mt) {
    const int r = wr * 64 + mt * 16 + ll;
    aoff[mt] = (r * 4 + (lh ^ ((r >> 1) & 3))) * 8;
  }
  #pragma unroll
  for (int nt = 0; nt < 4; ++nt) {
    const int r = wc * 64 + nt * 16 + ll;
    boff[nt] = (r * 4 + (lh ^ ((r >> 1) & 3))) * 8;
  }

  f32x4 acc[4][4];
  #pragma unroll
  for (int i = 0; i < 4; ++i)
    #pragma unroll
    for (int j = 0; j < 4; ++j) acc[i][j] = (f32x4){0.f, 0.f, 0.f, 0.f};

  for (int k0 = 0; k0 < K; k0 += 32) {
    __syncthreads();
    glds16(asrc0 + k0, &As[(size_t)(w * 128) * 8]);
    glds16(asrc1 + k0, &As[(size_t)(w * 128 + 64) * 8]);
    glds16(bsrc0 + k0, bdst0);
    glds16(bsrc1 + k0, bdst1);
    __syncthreads();

    short8 av[4], bv[4];
    #pragma unroll
    for (int mt = 0; mt < 4; ++mt) av[mt] = *(const short8*)&As[aoff[mt]];
    #pragma unroll
    for (int nt = 0; nt < 4; ++nt) bv[nt] = *(const short8*)&Bs[boff[nt]];
    #pragma unroll
    for (int mt = 0; mt < 4; ++mt)
      #pragma unroll
      for (int nt = 0; nt < 4; ++nt)
        acc[mt][nt] = mfma16(av[mt], bv[nt], acc[mt][nt]);
  }

  if constexpr (EPI == 1) {
    #pragma unroll
    for (int mt = 0; mt < 4; ++mt) {
      #pragma unroll
      for (int nt = 0; nt < 4; ++nt) {
        const int row = row0 + wr * 64 + mt * 16 + lh * 4;
        const int col = col0 + wc * 64 + nt * 16 + ll;
        const float bv_ = bias[col];
        #pragma unroll
        for (int j = 0; j < 4; ++j)
          C[(size_t)(row + j) * N + col] = acc[mt][nt][j] + bv_;
      }
    }
  } else if constexpr (EPI == 2) {
    #pragma unroll
    for (int mt = 0; mt < 4; ++mt) {
      #pragma unroll
      for (int nt = 0; nt < 4; ++nt) {
        const int rg = row0 + wr * 64 + mt * 16 + lh * 4;
        const int cg = col0 + wc * 64 + nt * 16 + ll;
        const int b = rg >> 12, n = rg & 4095;
        const int h = cg >> 6, dh = cg & 63;
        ushort4 o;
        o.x = f2bf(acc[mt][nt][0]); o.y = f2bf(acc[mt][nt][1]);
        o.z = f2bf(acc[mt][nt][2]); o.w = f2bf(acc[mt][nt][3]);
        *(ushort4*)&VT[(((size_t)b * 16 + h) * 64 + dh) * 4096 + n] = o;
      }
    }
  } else {   // EPI == 3
    const int hglob = (col0 >> 6) + wc;
    #pragma unroll
    for (int mt = 0; mt < 4; ++mt) {
      float rssq[4] = {0.f, 0.f, 0.f, 0.f};
      #pragma unroll
      for (int nt = 0; nt < 4; ++nt) {
        const int row = row0 + wr * 64 + mt * 16 + lh * 4;
        const int e = nt * 16 + ll;
        #pragma unroll
        for (int j = 0; j < 4; ++j) {
          const float v = acc[mt][nt][j];
          rssq[j] += v * v;
          const unsigned short hh = f2bf(v);
          const size_t base = ((size_t)(row + j) * 16 + hglob) * 128 + e;
          OHL[base] = hh;
          OHL[base + 64] = f2bf(v - bf2f(hh));
        }
      }
      #pragma unroll
      for (int j = 0; j < 4; ++j) {
        float s = rssq[j];
        s += __shfl_xor(s, 1, 64); s += __shfl_xor(s, 2, 64);
        s += __shfl_xor(s, 4, 64); s += __shfl_xor(s, 8, 64);
        if (ll == 0) {
          const int row = row0 + wr * 64 + mt * 16 + lh * 4 + j;
          DIAG[(((row >> 12) * 16 + hglob) << 12) + (row & 4095)] = HALF_DN2 * s;
        }
      }
    }
  }
}

// ---------------------------------------------------------------------------
// kside9: r7 structure (512 thr = 8 waves x 2 m-tiles, 512 blocks, 1-ahead K
// prefetch) + ONE change: __syncthreads() per iteration to keep the 8 waves
// in lockstep so they share each 16-row K/V tile through L1 instead of
// re-fetching after drift (r7 FETCH was 125 MB vs 50 MB ideal).
// ---------------------------------------------------------------------------
__global__ __launch_bounds__(512, 4) void kside9(const ushort_t* __restrict__ KHL,
                                                 const ushort_t* __restrict__ VT,
                                                 const ushort_t* __restrict__ PHI,
                                                 const ushort_t* __restrict__ PLO,
                                                 const float* __restrict__ DIAGK,
                                                 float* __restrict__ partC,
                                                 float* __restrict__ partK,
                                                 float* __restrict__ mw,
                                                 float* __restrict__ vsum,
                                                 unsigned* __restrict__ mxp)
{
  const int tid = threadIdx.x;
  const int l = tid & 63, mg = tid >> 6;          // 8 waves
  const int ll = l & 15, lh = l >> 4;
  const int blk = blockIdx.x;
  const int bh = blk >> 3, ck = blk & 7;
  const int b = bh >> 4, h = bh & 15;
  const int mbase = mg * 32;

  short8 pfh[2][2], pfl[2][2];
  #pragma unroll
  for (int mt = 0; mt < 2; ++mt)
    #pragma unroll
    for (int ks = 0; ks < 2; ++ks) {
      const size_t off = (size_t)(mbase + mt * 16 + ll) * 64 + ks * 32 + lh * 8;
      pfh[mt][ks] = *(const short8*)&PHI[off];
      pfl[mt][ks] = *(const short8*)&PLO[off];
    }

  f32x4 apv[2][4];
  #pragma unroll
  for (int i = 0; i < 2; ++i)
    #pragma unroll
    for (int j = 0; j < 4; ++j) apv[i][j] = (f32x4){0.f, 0.f, 0.f, 0.f};
  float kcp[2] = {0.f, 0.f};
  float vs[4] = {0.f, 0.f, 0.f, 0.f};
  float m_run = -1.0e30f, tmax = -1.0e30f;

  const int n0 = ck * 512;
  const ushort_t* krow = KHL + ((size_t)(b * NSEQ + n0 + ll) * 16 + h) * 128 + lh * 8;
  const ushort_t* vrow = VT + (size_t)bh * 64 * NSEQ + n0 + lh * 4;
  const float* drow = DIAGK + bh * 4096 + n0 + lh * 4;

  // K prefetch: current regs
  short8 kh0 = *(const short8*)(krow);
  short8 kh1 = *(const short8*)(krow + 32);
  short8 kl0 = *(const short8*)(krow + 64);
  short8 kl1 = *(const short8*)(krow + 96);

  for (int it = 0; it < 32; ++it) {
    // lockstep: all 8 waves enter the iteration together so the K/V tile
    // fetched by the first wave is L1-hot for the other seven.
    __syncthreads();

    // issue next-iteration K loads first (clamped; last iter reloads it=31)
    const int itn = (it < 31) ? it + 1 : 31;
    const ushort_t* kpn = krow + (size_t)itn * 16 * 2048;
    const short8 nh0 = *(const short8*)(kpn);
    const short8 nh1 = *(const short8*)(kpn + 32);
    const short8 nl0 = *(const short8*)(kpn + 64);
    const short8 nl1 = *(const short8*)(kpn + 96);

    // V / diag issued early, consumed late (self-hiding within the iter)
    const float4 dg4 = *(const float4*)(drow + it * 16);
    short4v vf[4];
    #pragma unroll
    for (int dt = 0; dt < 4; ++dt)
      vf[dt] = *(const short4v*)&vrow[(size_t)(dt * 16 + ll) * NSEQ + it * 16];

    f32x4 dda[2];
    #pragma unroll
    for (int mt = 0; mt < 2; ++mt) {
      f32x4 acc = (f32x4){0.f, 0.f, 0.f, 0.f};
      acc = mfma16(kh0, pfh[mt][0], acc); acc = mfma16(kh1, pfh[mt][1], acc);
      acc = mfma16(kh0, pfl[mt][0], acc); acc = mfma16(kh1, pfl[mt][1], acc);
      acc = mfma16(kl0, pfh[mt][0], acc); acc = mfma16(kl1, pfh[mt][1], acc);
      #pragma unroll
      for (int jr = 0; jr < 4; ++jr) acc[jr] *= DN;
      dda[mt] = acc;
    }

    float pm = -1.0e30f;
    #pragma unroll
    for (int mt = 0; mt < 2; ++mt)
      #pragma unroll
      for (int jr = 0; jr < 4; ++jr) pm = fmaxf(pm, dda[mt][jr]);
    tmax = fmaxf(tmax, pm);
    if (!__all(pm <= m_run + THR_DEFER)) {
      float pw = fmaxf(pm, m_run);
      pw = fmaxf(pw, __shfl_xor(pw, 1, 64));  pw = fmaxf(pw, __shfl_xor(pw, 2, 64));
      pw = fmaxf(pw, __shfl_xor(pw, 4, 64));  pw = fmaxf(pw, __shfl_xor(pw, 8, 64));
      pw = fmaxf(pw, __shfl_xor(pw, 16, 64)); pw = fmaxf(pw, __shfl_xor(pw, 32, 64));
      const float sc = __expf(m_run - pw);
      #pragma unroll
      for (int mt = 0; mt < 2; ++mt) {
        kcp[mt] *= sc;
        #pragma unroll
        for (int dt = 0; dt < 4; ++dt) apv[mt][dt] *= sc;
      }
      m_run = pw;
    }

    const float dgv[4] = {dg4.x, dg4.y, dg4.z, dg4.w};
    short4v qa[2];
    #pragma unroll
    for (int mt = 0; mt < 2; ++mt) {
      short4v o;
      float s = 0.f;
      #pragma unroll
      for (int jr = 0; jr < 4; ++jr) {
        const float kv = __expf(dda[mt][jr] - dgv[jr] - m_run);
        const unsigned short ub = f2bf(kv);
        o[jr] = (short)ub;
        s += bf2f(ub);
      }
      qa[mt] = o;
      kcp[mt] += s;
    }

    if (mg == 0) {
      #pragma unroll
      for (int dt = 0; dt < 4; ++dt)
        #pragma unroll
        for (int e = 0; e < 4; ++e) vs[dt] += bf2f((ushort_t)vf[dt][e]);
    }

    #pragma unroll
    for (int dt = 0; dt < 4; ++dt)
      #pragma unroll
      for (int mt = 0; mt < 2; ++mt)
        apv[mt][dt] = mfma16x16(qa[mt], vf[dt], apv[mt][dt]);

    kh0 = nh0; kh1 = nh1; kl0 = nl0; kl1 = nl1;
  }

  // epilogue
  #pragma unroll
  for (int mt = 0; mt < 2; ++mt) {
    float s = kcp[mt];
    s += __shfl_xor(s, 16, 64);
    s += __shfl_xor(s, 32, 64);
    if (lh == 0) partK[blk * 256 + mbase + mt * 16 + ll] = s;
  }
  #pragma unroll
  for (int mt = 0; mt < 2; ++mt)
    #pragma unroll
    for (int dt = 0; dt < 4; ++dt)
      #pragma unroll
      for (int jr = 0; jr < 4; ++jr) {
        const int m = mbase + mt * 16 + lh * 4 + jr;
        const int dh = dt * 16 + ll;
        partC[(size_t)blk * 16384 + (size_t)m * 64 + dh] = apv[mt][dt][jr];
      }
  if (mg == 0) {
    #pragma unroll
    for (int dt = 0; dt < 4; ++dt) {
      float s = vs[dt];
      s += __shfl_xor(s, 16, 64);
      s += __shfl_xor(s, 32, 64);
      if (lh == 0) atomicAdd(&vsum[bh * 64 + dt * 16 + ll], s);
    }
  }
  tmax = fmaxf(tmax, __shfl_xor(tmax, 1, 64));  tmax = fmaxf(tmax, __shfl_xor(tmax, 2, 64));
  tmax = fmaxf(tmax, __shfl_xor(tmax, 4, 64));  tmax = fmaxf(tmax, __shfl_xor(tmax, 8, 64));
  tmax = fmaxf(tmax, __shfl_xor(tmax, 16, 64)); tmax = fmaxf(tmax, __shfl_xor(tmax, 32, 64));
  if (l == 0) {
    atomicMax(mxp, __float_as_uint(tmax));
    mw[blk * 8 + mg] = m_run;
  }
}

// ---------------------------------------------------------------------------
// combine3: fold 8 partials/bh (8 waves' mw each); emit KCS fp32,
// CTH/CTL [bh][dh][m], CTSUM [bh][dh], KCSSUM [bh]. grid 256 = 64 bh x 4 mc.
// ---------------------------------------------------------------------------
__global__ __launch_bounds__(256) void combine3(const float* __restrict__ partC,
                                                const float* __restrict__ partK,
                                                const float* __restrict__ mw,
                                                const float* __restrict__ vsum,
                                                const unsigned* __restrict__ mxp,
                                                float* __restrict__ KCS,
                                                ushort_t* __restrict__ CTH,
                                                ushort_t* __restrict__ CTL,
                                                float* __restrict__ CTSUM,
                                                float* __restrict__ KCSSUM)
{
  const int tid = threadIdx.x;
  const int bh = blockIdx.x >> 2, mc = blockIdx.x & 3;
  const float MX = __uint_as_float(*mxp);
  float s[8][2];
  #pragma unroll
  for (int c = 0; c < 8; ++c)
    #pragma unroll
    for (int g = 0; g < 2; ++g)
      s[c][g] = RATIO * __expf(mw[(bh * 8 + c) * 8 + mc * 2 + g] - MX);

  __shared__ float ts[64][68];
  const int r = tid >> 4, c4 = (tid & 15) * 4;
  const float reps = RATIO * EPSF;
  const float4 v4 = *(const float4*)&vsum[bh * 64 + c4];
  #pragma unroll
  for (int i = 0; i < 4; ++i) {
    const int ml = r + i * 16;
    const int g = ml >> 5;
    const int m = mc * 64 + ml;
    float4 a;
    a.x = reps * v4.x; a.y = reps * v4.y; a.z = reps * v4.z; a.w = reps * v4.w;
    #pragma unroll
    for (int c = 0; c < 8; ++c) {
      const size_t blkc = bh * 8 + c;
      const float4 p = *(const float4*)&partC[blkc * 16384 + (size_t)m * 64 + c4];
      a.x += s[c][g] * p.x; a.y += s[c][g] * p.y;
      a.z += s[c][g] * p.z; a.w += s[c][g] * p.w;
    }
    *(float4*)&ts[ml][c4] = a;
  }
  if (tid < 64) {
    const int m = mc * 64 + tid;
    const int g = tid >> 5;
    float kv = reps * 4096.0f;
    #pragma unroll
    for (int c = 0; c < 8; ++c)
      kv += s[c][g] * partK[(bh * 8 + c) * 256 + m];
    KCS[bh * 256 + m] = kv;
    float ks = kv;
    #pragma unroll
    for (int off = 1; off < 64; off <<= 1) ks += __shfl_xor(ks, off, 64);
    if (tid == 0) atomicAdd(&KCSSUM[bh], ks);
  }
  __syncthreads();
  #pragma unroll
  for (int i = 0; i < 4; ++i) {
    const int dh = r + i * 16;
    ushort4 oh, ol;
    float csum = 0.f;
    #pragma unroll
    for (int k = 0; k < 4; ++k) {
      const float v = ts[c4 + k][dh];
      csum += v;
      const unsigned short hh = f2bf(v);
      ((unsigned short*)&oh)[k] = hh;
      ((unsigned short*)&ol)[k] = f2bf(v - bf2f(hh));
    }
    const size_t o = ((size_t)bh * 64 + dh) * MF + mc * 64 + c4;
    *(ushort4*)&CTH[o] = oh;
    *(ushort4*)&CTL[o] = ol;
    csum += __shfl_xor(csum, 1, 64); csum += __shfl_xor(csum, 2, 64);
    csum += __shfl_xor(csum, 4, 64); csum += __shfl_xor(csum, 8, 64);
    if ((tid & 15) == 0) atomicAdd(&CTSUM[bh * 64 + dh], csum);
  }
}

// ---------------------------------------------------------------------------
// qside7: online-over-mt q-side (defer-max, exact EPS restore via CTSUM/KCSSUM).
// grid 1024 = 64 bh x 16 tiles (256 rows). 512 thr (8 waves x 2 row-tiles).
// ---------------------------------------------------------------------------
__global__ __launch_bounds__(512, 2) void qside7(const ushort_t* __restrict__ QHL,
                                                 const ushort_t* __restrict__ PHI,
                                                 const ushort_t* __restrict__ PLO,
                                                 const float* __restrict__ DIAGQ,
                                                 const float* __restrict__ kcs,
                                                 const ushort_t* __restrict__ CTH,
                                                 const ushort_t* __restrict__ CTL,
                                                 const float* __restrict__ CTSUM,
                                                 const float* __restrict__ KCSSUM,
                                                 ushort_t* __restrict__ attb)
{
  extern __shared__ ushort_t lds[];
  ushort_t* pst = lds;               // 32768 ushorts (64 KB)
  ushort_t* ctf = lds + 32768;       // 32768 ushorts (64 KB)
  ushort_t* kcf = lds + 65536;       // 4096 ushorts (8 KB)
  float* ctsum_s = (float*)(lds + 69632);   // 64 floats

  const int tid = threadIdx.x;
  const int l = tid & 63, w = tid >> 6;
  const int ll = l & 15, lh = l >> 4;
  const int bh = blockIdx.x >> 4, qt = blockIdx.x & 15;
  const int b = bh >> 4, h = bh & 15;

  #pragma unroll
  for (int i = 0; i < 8; ++i) {
    const int f = tid + i * 512;
    const int fl = f & 63, r = f >> 6;
    const int p = r & 1, ks = (r >> 1) & 1, mt = r >> 2;
    const ushort_t* src = (p ? PLO : PHI) + (mt * 16 + (fl & 15)) * 64 + ks * 32 + (fl >> 4) * 8;
    *(short8*)&pst[f * 8] = *(const short8*)src;
  }
  #pragma unroll
  for (int i = 0; i < 16; ++i) {
    const int g = tid + i * 512;
    const int gl = g & 63, r = g >> 6;
    const int dt = r & 3, r2 = r >> 2, mt = r2 & 15, p = r2 >> 4;
    const ushort_t* src = (p ? CTL : CTH) +
        ((size_t)bh * 64 + dt * 16 + (gl & 15)) * MF + mt * 16 + (gl >> 4) * 4;
    *(ushort4*)&ctf[g * 4] = *(const ushort4*)src;
  }
  #pragma unroll
  for (int i = 0; i < 2; ++i) {
    const int u = tid + i * 512;
    const int ul = u & 63, mt = u >> 6;
    const int cll = ul & 15, clh = ul >> 4;
    ushort4 o = make_ushort4(0, 0, 0, 0);
    if (cll < 2) {
      #pragma unroll
      for (int e = 0; e < 4; ++e) {
        const float kv = kcs[bh * MF + mt * 16 + clh * 4 + e];
        const unsigned short hi = f2bf(kv);
        ((ushort_t*)&o)[e] = (cll == 0) ? hi : f2bf(kv - bf2f(hi));
      }
    }
    *(ushort4*)&kcf[u * 4] = o;
  }
  if (tid < 64) ctsum_s[tid] = CTSUM[bh * 64 + tid];
  const float kcss = KCSSUM[bh];

  const int nloc0 = qt * 256 + w * 32;
  const int rowb0 = b * NSEQ + nloc0;

  short8 qh0[2], ql0[2], qh1[2], ql1[2];
  #pragma unroll
  for (int ks = 0; ks < 2; ++ks) {
    const size_t base = ((size_t)(rowb0 + ll) * 16 + h) * 128 + ks * 32 + lh * 8;
    qh0[ks] = *(const short8*)&QHL[base];
    ql0[ks] = *(const short8*)&QHL[base + 64];
    qh1[ks] = *(const short8*)&QHL[base + (size_t)16 * 2048];
    ql1[ks] = *(const short8*)&QHL[base + (size_t)16 * 2048 + 64];
  }
  const float dg0 = DIAGQ[bh * 4096 + nloc0 + ll];
  const float dg1 = DIAGQ[bh * 4096 + nloc0 + 16 + ll];

  __syncthreads();

  f32x4 av0[4], av1[4];
  #pragma unroll
  for (int dt = 0; dt < 4; ++dt) {
    av0[dt] = (f32x4){0.f, 0.f, 0.f, 0.f};
    av1[dt] = (f32x4){0.f, 0.f, 0.f, 0.f};
  }
  f32x4 aK0 = (f32x4){0.f, 0.f, 0.f, 0.f};
  f32x4 aK1 = (f32x4){0.f, 0.f, 0.f, 0.f};
  float m0 = -1.0e30f, m1 = -1.0e30f, t0 = -1.0e30f, t1 = -1.0e30f;

  for (int mt = 0; mt < 16; ++mt) {
    const short8 ph0 = *(const short8*)&pst[((mt * 2 + 0) * 2 + 0) * 512 + l * 8];
    const short8 ph1 = *(const short8*)&pst[((mt * 2 + 1) * 2 + 0) * 512 + l * 8];
    const short8 pl0 = *(const short8*)&pst[((mt * 2 + 0) * 2 + 1) * 512 + l * 8];
    const short8 pl1 = *(const short8*)&pst[((mt * 2 + 1) * 2 + 1) * 512 + l * 8];
    f32x4 a0 = (f32x4){0.f, 0.f, 0.f, 0.f};
    f32x4 a1 = (f32x4){0.f, 0.f, 0.f, 0.f};
    a0 = mfma16(ph0, qh0[0], a0); a0 = mfma16(ph1, qh0[1], a0);
    a0 = mfma16(ph0, ql0[0], a0); a0 = mfma16(ph1, ql0[1], a0);
    a0 = mfma16(pl0, qh0[0], a0); a0 = mfma16(pl1, qh0[1], a0);
    a1 = mfma16(ph0, qh1[0], a1); a1 = mfma16(ph1, qh1[1], a1);
    a1 = mfma16(ph0, ql1[0], a1); a1 = mfma16(ph1, ql1[1], a1);
    a1 = mfma16(pl0, qh1[0], a1); a1 = mfma16(pl1, qh1[1], a1);
    #pragma unroll
    for (int jr = 0; jr < 4; ++jr) { a0[jr] *= DN; a1[jr] *= DN; }

    const float pm0 = fmaxf(fmaxf(a0[0], a0[1]), fmaxf(a0[2], a0[3]));
    const float pm1 = fmaxf(fmaxf(a1[0], a1[1]), fmaxf(a1[2], a1[3]));
    t0 = fmaxf(t0, pm0);
    t1 = fmaxf(t1, pm1);
    if (!__all((pm0 <= m0 + THR_DEFER) && (pm1 <= m1 + THR_DEFER))) {
      float pw0 = fmaxf(pm0, m0), pw1 = fmaxf(pm1, m1);
      pw0 = fmaxf(pw0, __shfl_xor(pw0, 16, 64)); pw0 = fmaxf(pw0, __shfl_xor(pw0, 32, 64));
      pw1 = fmaxf(pw1, __shfl_xor(pw1, 16, 64)); pw1 = fmaxf(pw1, __shfl_xor(pw1, 32, 64));
      const float sc0l = __expf(m0 - pw0);
      const float sc1l = __expf(m1 - pw1);
      m0 = pw0; m1 = pw1;
      #pragma unroll
      for (int jr = 0; jr < 4; ++jr) {
        const int src = (l & 48) | (lh * 4 + jr);
        const float s0 = __shfl(sc0l, src, 64);
        const float s1 = __shfl(sc1l, src, 64);
        #pragma unroll
        for (int dt = 0; dt < 4; ++dt) { av0[dt][jr] *= s0; av1[dt][jr] *= s1; }
        aK0[jr] *= s0; aK1[jr] *= s1;
      }
    }

    short4v qp0, qp1;
    #pragma unroll
    for (int jr = 0; jr < 4; ++jr) {
      qp0[jr] = (short)f2bf(__expf(a0[jr] - dg0 - m0));
      qp1[jr] = (short)f2bf(__expf(a1[jr] - dg1 - m1));
    }
    const short4v kcv = *(const short4v*)&kcf[mt * 256 + l * 4];
    aK0 = mfma16x16(qp0, kcv, aK0);
    aK1 = mfma16x16(qp1, kcv, aK1);
    #pragma unroll
    for (int dt = 0; dt < 4; ++dt) {
      const short4v ch = *(const short4v*)&ctf[(mt * 4 + dt) * 256 + l * 4];
      const short4v cl = *(const short4v*)&ctf[((16 + mt) * 4 + dt) * 256 + l * 4];
      av0[dt] = mfma16x16(qp0, ch, av0[dt]);
      av0[dt] = mfma16x16(qp0, cl, av0[dt]);
      av1[dt] = mfma16x16(qp1, ch, av1[dt]);
      av1[dt] = mfma16x16(qp1, cl, av1[dt]);
    }
  }

  // epilogue: true row max, per-output-row rescale, exact EPS restore
  t0 = fmaxf(t0, __shfl_xor(t0, 16, 64)); t0 = fmaxf(t0, __shfl_xor(t0, 32, 64));
  t1 = fmaxf(t1, __shfl_xor(t1, 16, 64)); t1 = fmaxf(t1, __shfl_xor(t1, 32, 64));

  float e0s[4], e1s[4], di0[4], di1[4];
  #pragma unroll
  for (int jr = 0; jr < 4; ++jr) {
    const int src = (l & 48) | (lh * 4 + jr);
    e0s[jr] = __expf(__shfl(m0, src, 64) - __shfl(t0, src, 64));
    e1s[jr] = __expf(__shfl(m1, src, 64) - __shfl(t1, src, 64));
    const float h0 = __shfl(aK0[jr], (l & 48), 64);
    const float lo0 = __shfl(aK0[jr], (l & 48) | 1, 64);
    const float h1 = __shfl(aK1[jr], (l & 48), 64);
    const float lo1 = __shfl(aK1[jr], (l & 48) | 1, 64);
    di0[jr] = 1.0f / (e0s[jr] * (h0 + lo0) + EPSF * kcss);
    di1[jr] = 1.0f / (e1s[jr] * (h1 + lo1) + EPSF * kcss);
  }

  #pragma unroll
  for (int dt = 0; dt < 4; ++dt) {
    const int col = h * DHD + dt * 16 + ll;
    const float cts = EPSF * ctsum_s[dt * 16 + ll];
    #pragma unroll
    for (int jr = 0; jr < 4; ++jr) {
      const float num0 = e0s[jr] * av0[dt][jr] + cts;
      const float num1 = e1s[jr] * av1[dt][jr] + cts;
      attb[(size_t)(rowb0 + lh * 4 + jr) * DM + col] = f2bf(num0 * di0[jr]);
      attb[(size_t)(rowb0 + 16 + lh * 4 + jr) * DM + col] = f2bf(num1 * di1[jr]);
    }
  }
}

// ---------------------------------------------------------------------------
extern "C" void kernel_launch(void* const* d_in, const int* in_sizes, int n_in,
                              void* d_out, int out_size, void* d_ws, size_t ws_size,
                              hipStream_t stream)
{
  const float* x  = (const float*)d_in[0];
  const float* Wq = (const float*)d_in[1];
  const float* Wk = (const float*)d_in[2];
  const float* Wv = (const float*)d_in[3];
  const float* Wo = (const float*)d_in[4];
  const float* bo = (const float*)d_in[5];
  const float* P  = (const float*)d_in[6];
  float* out = (float*)d_out;

  char* wp = (char*)d_ws;
  ushort_t* QHL   = (ushort_t*)(wp + 0);            // 64 MB [row][h][128]
  ushort_t* KHL   = (ushort_t*)(wp + 67108864);     // 64 MB (ATTB overlays)
  ushort_t* VT    = (ushort_t*)(wp + 134217728);    // 32 MB [bh][dh][n]
  ushort_t* Wqt   = (ushort_t*)(wp + 167772160);
  ushort_t* Wkt   = (ushort_t*)(wp + 169869312);
  ushort_t* Wvt   = (ushort_t*)(wp + 171966464);
  ushort_t* Wot   = (ushort_t*)(wp + 174063616);
  ushort_t* PHI   = (ushort_t*)(wp + 176160768);
  ushort_t* PLO   = (ushort_t*)(wp + 176193536);
  float*    DIAGQ = (float*)(wp + 176226304);       // 1 MB
  float*    DIAGK = (float*)(wp + 177274880);       // 1 MB
  float*    PARTK = (float*)(wp + 178323456);       // 512 KB
  float*    MW    = (float*)(wp + 178847744);       // 16 KB
  float*    VSUM  = (float*)(wp + 178864128);       // 16 KB
  unsigned* MX    = (unsigned*)(wp + 178880512);    // 256 B
  float*    CTSUM = (float*)(wp + 178880768);       // 16 KB
  float*    KCSSUM= (float*)(wp + 178897152);       // 256 B
  float*    KCS   = (float*)(wp + 178897408);       // 64 KB
  ushort_t* CTH   = (ushort_t*)(wp + 178962944);    // 2 MB
  ushort_t* CTL   = (ushort_t*)(wp + 181060096);    // 2 MB -> end 183157248
  ushort_t* ATTB  = KHL;

  // scratch carved out of d_out (fully overwritten by the final Wo-GEMM):
  float*    PARTC = (float*)d_out;                           // 32 MB
  ushort_t* XB    = (ushort_t*)((char*)d_out + 33554432);    // 32 MB

  dim3 tg(16, 16);
  wtrans<<<tg, 256, 0, stream>>>(Wq, Wqt);
  wtrans<<<tg, 256, 0, stream>>>(Wk, Wkt);
  wtrans<<<tg, 256, 0, stream>>>(Wv, Wvt);
  wtrans<<<tg, 256, 0, stream>>>(Wo, Wot);
  psplit<<<64, 256, 0, stream>>>(P, PHI, PLO);
  xconv<<<8192, 256, 0, stream>>>(x, XB);
  hipMemsetAsync(VSUM, 0, 33280, stream);   // VSUM + MX + CTSUM + KCSSUM

  gemm_k<3><<<1024, 256, 0, stream>>>(XB, Wqt, nullptr, nullptr, nullptr, QHL, DIAGQ);
  gemm_k<3><<<1024, 256, 0, stream>>>(XB, Wkt, nullptr, nullptr, nullptr, KHL, DIAGK);
  gemm_k<2><<<1024, 256, 0, stream>>>(XB, Wvt, nullptr, nullptr, VT, nullptr, nullptr);

  kside9<<<512, 512, 0, stream>>>(KHL, VT, PHI, PLO, DIAGK, PARTC, PARTK, MW, VSUM, MX);
  combine3<<<256, 256, 0, stream>>>(PARTC, PARTK, MW, VSUM, MX, KCS, CTH, CTL, CTSUM, KCSSUM);
  qside7<<<1024, 512, 139520, stream>>>(QHL, PHI, PLO, DIAGQ, KCS, CTH, CTL, CTSUM, KCSSUM, ATTB);

  gemm_k<1><<<1024, 256, 0, stream>>>(ATTB, Wot, bo, out, nullptr, nullptr, nullptr);
}

// Round 10
// 450.878 us; speedup vs baseline: 1.1655x; 1.1655x over previous
//
#include <hip/hip_runtime.h>
#include <math.h>

#define NB 4
#define NSEQ 4096
#define DM 1024
#define NHEAD 16
#define DHD 64
#define MF 256
#define ROWS 16384

#define DN 0.35355339059327373f
#define RATIO 0.0625f
#define HALF_DN2 0.0625f
#define EPSF 1.0e-4f
#define THR_DEFER 4.0f

typedef __attribute__((ext_vector_type(4))) float f32x4;
typedef __attribute__((ext_vector_type(8))) short short8;
typedef __attribute__((ext_vector_type(4))) short short4v;
typedef __attribute__((ext_vector_type(8))) __bf16 bf16x8;
typedef unsigned short ushort_t;

__device__ __forceinline__ unsigned short f2bf(float f) {
  unsigned int u = __builtin_bit_cast(unsigned int, f);
  u += 0x7FFFu + ((u >> 16) & 1u);
  return (unsigned short)(u >> 16);
}
__device__ __forceinline__ float bf2f(unsigned short h) {
  unsigned int u = ((unsigned int)h) << 16;
  return __builtin_bit_cast(float, u);
}

__device__ __forceinline__ f32x4 mfma16(short8 a, short8 b, f32x4 c) {
  return __builtin_amdgcn_mfma_f32_16x16x32_bf16(
      __builtin_bit_cast(bf16x8, a), __builtin_bit_cast(bf16x8, b), c, 0, 0, 0);
}

// 16x16x16 bf16 MFMA (K=16). Fragment mappings validated end-to-end in r4/r5.
__device__ __forceinline__ f32x4 mfma16x16(short4v a, short4v b, f32x4 c) {
#if __has_builtin(__builtin_amdgcn_mfma_f32_16x16x16bf16_1k)
  return __builtin_amdgcn_mfma_f32_16x16x16bf16_1k(a, b, c, 0, 0, 0);
#elif __has_builtin(__builtin_amdgcn_mfma_f32_16x16x16_bf16)
  typedef __attribute__((ext_vector_type(4))) __bf16 bf16x4;
  return __builtin_amdgcn_mfma_f32_16x16x16_bf16(
      __builtin_bit_cast(bf16x4, a), __builtin_bit_cast(bf16x4, b), c, 0, 0, 0);
#else
  asm volatile("s_nop 1\n\t"
               "v_mfma_f32_16x16x16_bf16 %0, %1, %2, %0\n\t"
               "s_nop 7"
               : "+v"(c) : "v"(a), "v"(b));
  return c;
#endif
}

__device__ __forceinline__ void glds16(const void* g, void* l) {
  __builtin_amdgcn_global_load_lds(
      (const __attribute__((address_space(1))) unsigned int*)g,
      (__attribute__((address_space(3))) unsigned int*)l, 16, 0, 0);
}

// ---------------------------------------------------------------------------
// Weight transpose-cast: Wt[n][k] = bf16(W[k][n]).
// ---------------------------------------------------------------------------
__global__ __launch_bounds__(256) void wtrans(const float* __restrict__ W,
                                              ushort_t* __restrict__ Wt)
{
  __shared__ float ts[64][68];
  const int tid = threadIdx.x;
  const int k0 = blockIdx.y * 64, n0 = blockIdx.x * 64;
  const int r = tid >> 4, c4 = (tid & 15) * 4;
  #pragma unroll
  for (int i = 0; i < 4; ++i) {
    float4 v = *(const float4*)&W[(size_t)(k0 + r + i * 16) * DM + n0 + c4];
    *(float4*)&ts[r + i * 16][c4] = v;
  }
  __syncthreads();
  #pragma unroll
  for (int i = 0; i < 4; ++i) {
    const int n = r + i * 16;
    ushort4 o;
    o.x = f2bf(ts[c4 + 0][n]); o.y = f2bf(ts[c4 + 1][n]);
    o.z = f2bf(ts[c4 + 2][n]); o.w = f2bf(ts[c4 + 3][n]);
    *(ushort4*)&Wt[(size_t)(n0 + n) * DM + k0 + c4] = o;
  }
}

// ---------------------------------------------------------------------------
__global__ __launch_bounds__(256) void psplit(const float* __restrict__ P,
                                              ushort_t* __restrict__ PHI,
                                              ushort_t* __restrict__ PLO)
{
  const int i = blockIdx.x * 256 + threadIdx.x;
  const float v = P[i];
  const unsigned short h = f2bf(v);
  PHI[i] = h;
  PLO[i] = f2bf(v - bf2f(h));
}

// ---------------------------------------------------------------------------
__global__ __launch_bounds__(256) void xconv(const float* __restrict__ x,
                                             ushort_t* __restrict__ xb)
{
  const size_t i = ((size_t)blockIdx.x * 256 + threadIdx.x) * 8;
  const float4 a = *(const float4*)&x[i];
  const float4 c = *(const float4*)&x[i + 4];
  short8 o;
  o[0] = f2bf(a.x); o[1] = f2bf(a.y); o[2] = f2bf(a.z); o[3] = f2bf(a.w);
  o[4] = f2bf(c.x); o[5] = f2bf(c.y); o[6] = f2bf(c.z); o[7] = f2bf(c.w);
  *(short8*)&xb[i] = o;
}

// ---------------------------------------------------------------------------
// bf16 MFMA GEMM: C[16384,1024] = A @ Bt^T. 128x128, BK=32. (unchanged r5)
// EPI: 1=C fp32+bias, 2=VT bf16 [bh][dh][n], 3=hi|lo [row][h][128] + diag.
// ---------------------------------------------------------------------------
template<int EPI>
__global__ __launch_bounds__(256) void gemm_k(const ushort_t* __restrict__ Ab,
                                              const ushort_t* __restrict__ Bt,
                                              const float* __restrict__ bias,
                                              float* __restrict__ C,
                                              ushort_t* __restrict__ VT,
                                              ushort_t* __restrict__ OHL,
                                              float* __restrict__ DIAG)
{
  constexpr int K = DM, N = DM;
  __shared__ ushort_t As[128 * 32];
  __shared__ ushort_t Bs[128 * 32];

  const int tid = threadIdx.x;
  const int l = tid & 63, w = tid >> 6;
  const int ll = l & 15, lh = l >> 4;
  const int wr = w >> 1, wc = w & 1;

  const int bid = blockIdx.x;
  const int swz = (bid & 7) * ((int)gridDim.x >> 3) + (bid >> 3);
  const int bm = swz >> 3, bn = swz & 7;
  const int row0 = bm * 128, col0 = bn * 128;

  const int pb0 = w * 128 + l, pb1 = pb0 + 64;
  const int brow0 = pb0 >> 2, bkq0 = (pb0 & 3) ^ ((brow0 >> 1) & 3);
  const int brow1 = pb1 >> 2, bkq1 = (pb1 & 3) ^ ((brow1 >> 1) & 3);
  const ushort_t* bsrc0 = Bt + (size_t)(col0 + brow0) * K + bkq0 * 8;
  const ushort_t* bsrc1 = Bt + (size_t)(col0 + brow1) * K + bkq1 * 8;
  ushort_t* bdst0 = &Bs[(size_t)(w * 128) * 8];
  ushort_t* bdst1 = &Bs[(size_t)(w * 128 + 64) * 8];

  const ushort_t* asrc0 = Ab + (size_t)(row0 + brow0) * K + bkq0 * 8;
  const ushort_t* asrc1 = Ab + (size_t)(row0 + brow1) * K + bkq1 * 8;

  int aoff[4], boff[4];
  #pragma unroll
  for (int mt = 0; mt < 4; ++mt) {
    const int r = wr * 64 + mt * 16 + ll;
    aoff[mt] = (r * 4 + (lh ^ ((r >> 1) & 3))) * 8;
  }
  #pragma unroll
  for (int nt = 0; nt < 4; ++nt) {
    const int r = wc * 64 + nt * 16 + ll;
    boff[nt] = (r * 4 + (lh ^ ((r >> 1) & 3))) * 8;
  }

  f32x4 acc[4][4];
  #pragma unroll
  for (int i = 0; i < 4; ++i)
    #pragma unroll
    for (int j = 0; j < 4; ++j) acc[i][j] = (f32x4){0.f, 0.f, 0.f, 0.f};

  for (int k0 = 0; k0 < K; k0 += 32) {
    __syncthreads();
    glds16(asrc0 + k0, &As[(size_t)(w * 128) * 8]);
    glds16(asrc1 + k0, &As[(size_t)(w * 128 + 64) * 8]);
    glds16(bsrc0 + k0, bdst0);
    glds16(bsrc1 + k0, bdst1);
    __syncthreads();

    short8 av[4], bv[4];
    #pragma unroll
    for (int mt = 0; mt < 4; ++mt) av[mt] = *(const short8*)&As[aoff[mt]];
    #pragma unroll
    for (int nt = 0; nt < 4; ++nt) bv[nt] = *(const short8*)&Bs[boff[nt]];
    #pragma unroll
    for (int mt = 0; mt < 4; ++mt)
      #pragma unroll
      for (int nt = 0; nt < 4; ++nt)
        acc[mt][nt] = mfma16(av[mt], bv[nt], acc[mt][nt]);
  }

  if constexpr (EPI == 1) {
    #pragma unroll
    for (int mt = 0; mt < 4; ++mt) {
      #pragma unroll
      for (int nt = 0; nt < 4; ++nt) {
        const int row = row0 + wr * 64 + mt * 16 + lh * 4;
        const int col = col0 + wc * 64 + nt * 16 + ll;
        const float bv_ = bias[col];
        #pragma unroll
        for (int j = 0; j < 4; ++j)
          C[(size_t)(row + j) * N + col] = acc[mt][nt][j] + bv_;
      }
    }
  } else if constexpr (EPI == 2) {
    #pragma unroll
    for (int mt = 0; mt < 4; ++mt) {
      #pragma unroll
      for (int nt = 0; nt < 4; ++nt) {
        const int rg = row0 + wr * 64 + mt * 16 + lh * 4;
        const int cg = col0 + wc * 64 + nt * 16 + ll;
        const int b = rg >> 12, n = rg & 4095;
        const int h = cg >> 6, dh = cg & 63;
        ushort4 o;
        o.x = f2bf(acc[mt][nt][0]); o.y = f2bf(acc[mt][nt][1]);
        o.z = f2bf(acc[mt][nt][2]); o.w = f2bf(acc[mt][nt][3]);
        *(ushort4*)&VT[(((size_t)b * 16 + h) * 64 + dh) * 4096 + n] = o;
      }
    }
  } else {   // EPI == 3
    const int hglob = (col0 >> 6) + wc;
    #pragma unroll
    for (int mt = 0; mt < 4; ++mt) {
      float rssq[4] = {0.f, 0.f, 0.f, 0.f};
      #pragma unroll
      for (int nt = 0; nt < 4; ++nt) {
        const int row = row0 + wr * 64 + mt * 16 + lh * 4;
        const int e = nt * 16 + ll;
        #pragma unroll
        for (int j = 0; j < 4; ++j) {
          const float v = acc[mt][nt][j];
          rssq[j] += v * v;
          const unsigned short hh = f2bf(v);
          const size_t base = ((size_t)(row + j) * 16 + hglob) * 128 + e;
          OHL[base] = hh;
          OHL[base + 64] = f2bf(v - bf2f(hh));
        }
      }
      #pragma unroll
      for (int j = 0; j < 4; ++j) {
        float s = rssq[j];
        s += __shfl_xor(s, 1, 64); s += __shfl_xor(s, 2, 64);
        s += __shfl_xor(s, 4, 64); s += __shfl_xor(s, 8, 64);
        if (ll == 0) {
          const int row = row0 + wr * 64 + mt * 16 + lh * 4 + j;
          DIAG[(((row >> 12) * 16 + hglob) << 12) + (row & 4095)] = HALF_DN2 * s;
        }
      }
    }
  }
}

// ---------------------------------------------------------------------------
// kside5w: r5's kside5 (proven 91 us; 512 blocks = 64 bh x 8 chunks, 4 waves
// x 64 m, one-reader-per-row, live 1-ahead K prefetch, NO barriers) with ONE
// change: 32 rows per iteration as two independent 16-row groups (A/B) ->
// 2x ILP on the load->dd->exp->PV chain, half the latency events per row.
// Math exact vs r5 (defer-max rescale is timing-invariant).
// ---------------------------------------------------------------------------
__global__ __launch_bounds__(256, 2) void kside5w(const ushort_t* __restrict__ KHL,
                                                  const ushort_t* __restrict__ VT,
                                                  const ushort_t* __restrict__ PHI,
                                                  const ushort_t* __restrict__ PLO,
                                                  const float* __restrict__ DIAGK,
                                                  float* __restrict__ partC,
                                                  float* __restrict__ partK,
                                                  float* __restrict__ mw,
                                                  float* __restrict__ vsum,
                                                  unsigned* __restrict__ mxp)
{
  const int tid = threadIdx.x;
  const int l = tid & 63, mg = tid >> 6;
  const int ll = l & 15, lh = l >> 4;
  const int blk = blockIdx.x;
  const int bh = blk >> 3, ck = blk & 7;
  const int b = bh >> 4, h = bh & 15;

  short8 pfh[4][2], pfl[4][2];
  #pragma unroll
  for (int mt = 0; mt < 4; ++mt)
    #pragma unroll
    for (int ks = 0; ks < 2; ++ks) {
      const size_t off = (size_t)(mg * 64 + mt * 16 + ll) * 64 + ks * 32 + lh * 8;
      pfh[mt][ks] = *(const short8*)&PHI[off];
      pfl[mt][ks] = *(const short8*)&PLO[off];
    }

  f32x4 apv[4][4];
  #pragma unroll
  for (int i = 0; i < 4; ++i)
    #pragma unroll
    for (int j = 0; j < 4; ++j) apv[i][j] = (f32x4){0.f, 0.f, 0.f, 0.f};
  float kcp[4] = {0.f, 0.f, 0.f, 0.f};
  float vs[4] = {0.f, 0.f, 0.f, 0.f};
  float m_run = -1.0e30f, tmax = -1.0e30f;

  const int n0 = ck * 512;
  const ushort_t* krow = KHL + ((size_t)(b * NSEQ + n0 + ll) * 16 + h) * 128 + lh * 8;
  const ushort_t* vrow = VT + (size_t)bh * 64 * NSEQ + n0 + lh * 4;
  const float* drow = DIAGK + bh * 4096 + n0 + lh * 4;

  // current K regs for groups A (rows +0..15) and B (rows +16..31)
  short8 kA[4], kB[4];
  #pragma unroll
  for (int q = 0; q < 4; ++q) {
    kA[q] = *(const short8*)(krow + q * 32);
    kB[q] = *(const short8*)(krow + 16 * 2048 + q * 32);
  }

  for (int it = 0; it < 16; ++it) {
    // 1-ahead K prefetch (clamped; last iter reloads it=15)
    const int itn = (it < 15) ? it + 1 : 15;
    const ushort_t* kpA = krow + (size_t)itn * 32 * 2048;
    const ushort_t* kpB = kpA + 16 * 2048;
    short8 nA[4], nB[4];
    #pragma unroll
    for (int q = 0; q < 4; ++q) {
      nA[q] = *(const short8*)(kpA + q * 32);
      nB[q] = *(const short8*)(kpB + q * 32);
    }

    // V / diag issued early, consumed late (~full dd+exp phase as cover)
    const float4 dgA = *(const float4*)(drow + it * 32);
    const float4 dgB = *(const float4*)(drow + it * 32 + 16);
    short4v vfA[4], vfB[4];
    #pragma unroll
    for (int dt = 0; dt < 4; ++dt) {
      vfA[dt] = *(const short4v*)&vrow[(size_t)(dt * 16 + ll) * NSEQ + it * 32];
      vfB[dt] = *(const short4v*)&vrow[(size_t)(dt * 16 + ll) * NSEQ + it * 32 + 16];
    }

    // dd for both groups (independent MFMA chains interleave)
    f32x4 ddA[4], ddB[4];
    #pragma unroll
    for (int mt = 0; mt < 4; ++mt) {
      f32x4 a = (f32x4){0.f, 0.f, 0.f, 0.f};
      f32x4 c = (f32x4){0.f, 0.f, 0.f, 0.f};
      a = mfma16(kA[0], pfh[mt][0], a); a = mfma16(kA[1], pfh[mt][1], a);
      a = mfma16(kA[0], pfl[mt][0], a); a = mfma16(kA[1], pfl[mt][1], a);
      a = mfma16(kA[2], pfh[mt][0], a); a = mfma16(kA[3], pfh[mt][1], a);
      c = mfma16(kB[0], pfh[mt][0], c); c = mfma16(kB[1], pfh[mt][1], c);
      c = mfma16(kB[0], pfl[mt][0], c); c = mfma16(kB[1], pfl[mt][1], c);
      c = mfma16(kB[2], pfh[mt][0], c); c = mfma16(kB[3], pfh[mt][1], c);
      #pragma unroll
      for (int jr = 0; jr < 4; ++jr) { a[jr] *= DN; c[jr] *= DN; }
      ddA[mt] = a; ddB[mt] = c;
    }

    float pm = -1.0e30f;
    #pragma unroll
    for (int mt = 0; mt < 4; ++mt)
      #pragma unroll
      for (int jr = 0; jr < 4; ++jr)
        pm = fmaxf(pm, fmaxf(ddA[mt][jr], ddB[mt][jr]));
    tmax = fmaxf(tmax, pm);
    if (!__all(pm <= m_run + THR_DEFER)) {
      float pw = fmaxf(pm, m_run);
      pw = fmaxf(pw, __shfl_xor(pw, 1, 64));  pw = fmaxf(pw, __shfl_xor(pw, 2, 64));
      pw = fmaxf(pw, __shfl_xor(pw, 4, 64));  pw = fmaxf(pw, __shfl_xor(pw, 8, 64));
      pw = fmaxf(pw, __shfl_xor(pw, 16, 64)); pw = fmaxf(pw, __shfl_xor(pw, 32, 64));
      const float sc = __expf(m_run - pw);
      #pragma unroll
      for (int mt = 0; mt < 4; ++mt) {
        kcp[mt] *= sc;
        #pragma unroll
        for (int dt = 0; dt < 4; ++dt) apv[mt][dt] *= sc;
      }
      m_run = pw;
    }

    const float dgvA[4] = {dgA.x, dgA.y, dgA.z, dgA.w};
    const float dgvB[4] = {dgB.x, dgB.y, dgB.z, dgB.w};
    short4v qaA[4], qaB[4];
    #pragma unroll
    for (int mt = 0; mt < 4; ++mt) {
      short4v oA, oB;
      float s = 0.f;
      #pragma unroll
      for (int jr = 0; jr < 4; ++jr) {
        const float kvA = __expf(ddA[mt][jr] - dgvA[jr] - m_run);
        const float kvB = __expf(ddB[mt][jr] - dgvB[jr] - m_run);
        const unsigned short uA = f2bf(kvA);
        const unsigned short uB = f2bf(kvB);
        oA[jr] = (short)uA;
        oB[jr] = (short)uB;
        s += bf2f(uA) + bf2f(uB);
      }
      qaA[mt] = oA;
      qaB[mt] = oB;
      kcp[mt] += s;
    }

    if (mg == 0) {
      #pragma unroll
      for (int dt = 0; dt < 4; ++dt)
        #pragma unroll
        for (int e = 0; e < 4; ++e)
          vs[dt] += bf2f((ushort_t)vfA[dt][e]) + bf2f((ushort_t)vfB[dt][e]);
    }

    #pragma unroll
    for (int dt = 0; dt < 4; ++dt)
      #pragma unroll
      for (int mt = 0; mt < 4; ++mt) {
        apv[mt][dt] = mfma16x16(qaA[mt], vfA[dt], apv[mt][dt]);
        apv[mt][dt] = mfma16x16(qaB[mt], vfB[dt], apv[mt][dt]);
      }

    #pragma unroll
    for (int q = 0; q < 4; ++q) { kA[q] = nA[q]; kB[q] = nB[q]; }
  }

  // epilogue (identical to r5 kside5)
  #pragma unroll
  for (int mt = 0; mt < 4; ++mt) {
    float s = kcp[mt];
    s += __shfl_xor(s, 16, 64);
    s += __shfl_xor(s, 32, 64);
    if (lh == 0) partK[blk * 256 + mg * 64 + mt * 16 + ll] = s;
  }
  #pragma unroll
  for (int mt = 0; mt < 4; ++mt)
    #pragma unroll
    for (int dt = 0; dt < 4; ++dt)
      #pragma unroll
      for (int jr = 0; jr < 4; ++jr) {
        const int m = mg * 64 + mt * 16 + lh * 4 + jr;
        const int dh = dt * 16 + ll;
        partC[(size_t)blk * 16384 + (size_t)m * 64 + dh] = apv[mt][dt][jr];
      }
  if (mg == 0) {
    #pragma unroll
    for (int dt = 0; dt < 4; ++dt) {
      float s = vs[dt];
      s += __shfl_xor(s, 16, 64);
      s += __shfl_xor(s, 32, 64);
      if (lh == 0) atomicAdd(&vsum[bh * 64 + dt * 16 + ll], s);
    }
  }
  tmax = fmaxf(tmax, __shfl_xor(tmax, 1, 64));  tmax = fmaxf(tmax, __shfl_xor(tmax, 2, 64));
  tmax = fmaxf(tmax, __shfl_xor(tmax, 4, 64));  tmax = fmaxf(tmax, __shfl_xor(tmax, 8, 64));
  tmax = fmaxf(tmax, __shfl_xor(tmax, 16, 64)); tmax = fmaxf(tmax, __shfl_xor(tmax, 32, 64));
  if (l == 0) {
    atomicMax(mxp, __float_as_uint(tmax));
    mw[blk * 4 + mg] = m_run;
  }
}

// ---------------------------------------------------------------------------
// combine: ctx[m][dh] = ratio*(sum_c e^{mw-MX}*partC + eps*VSUM[dh]);
// kcs[m] = ratio*(sum_c e^{mw-MX}*partK + eps*4096). Writes CTH/CTL [bh][dh][m]
// (hi/lo split) + KCS fp32. grid 256 = 64 bh x 4 m-chunks.
// ---------------------------------------------------------------------------
__global__ __launch_bounds__(256) void combine(const float* __restrict__ partC,
                                               const float* __restrict__ partK,
                                               const float* __restrict__ mw,
                                               const float* __restrict__ vsum,
                                               const unsigned* __restrict__ mxp,
                                               float* __restrict__ KCS,
                                               ushort_t* __restrict__ CTH,
                                               ushort_t* __restrict__ CTL)
{
  const int tid = threadIdx.x;
  const int bh = blockIdx.x >> 2, mc = blockIdx.x & 3;
  const float MX = __uint_as_float(*mxp);
  float s[8];
  #pragma unroll
  for (int c = 0; c < 8; ++c)
    s[c] = RATIO * __expf(mw[(bh * 8 + c) * 4 + mc] - MX);

  __shared__ float ts[64][68];
  const int r = tid >> 4, c4 = (tid & 15) * 4;
  const float reps = RATIO * EPSF;
  const float4 v4 = *(const float4*)&vsum[bh * 64 + c4];
  #pragma unroll
  for (int i = 0; i < 4; ++i) {
    const int ml = r + i * 16;
    float4 a;
    a.x = reps * v4.x; a.y = reps * v4.y; a.z = reps * v4.z; a.w = reps * v4.w;
    #pragma unroll
    for (int c = 0; c < 8; ++c) {
      const float4 p = *(const float4*)&partC[(size_t)(bh * 8 + c) * 16384 +
                                              (size_t)(mc * 64 + ml) * 64 + c4];
      a.x += s[c] * p.x; a.y += s[c] * p.y; a.z += s[c] * p.z; a.w += s[c] * p.w;
    }
    *(float4*)&ts[ml][c4] = a;
  }
  if (tid < 64) {
    const int m = mc * 64 + tid;
    float kv = reps * 4096.0f;
    #pragma unroll
    for (int c = 0; c < 8; ++c) kv += s[c] * partK[(bh * 8 + c) * 256 + m];
    KCS[bh * 256 + m] = kv;
  }
  __syncthreads();
  #pragma unroll
  for (int i = 0; i < 4; ++i) {
    const int dh = r + i * 16;
    ushort4 oh, ol;
    #pragma unroll
    for (int k = 0; k < 4; ++k) {
      const float v = ts[c4 + k][dh];
      const unsigned short hh = f2bf(v);
      ((unsigned short*)&oh)[k] = hh;
      ((unsigned short*)&ol)[k] = f2bf(v - bf2f(hh));
    }
    const size_t o = ((size_t)bh * 64 + dh) * MF + mc * 64 + c4;
    *(ushort4*)&CTH[o] = oh;
    *(ushort4*)&CTL[o] = ol;
  }
}

// ---------------------------------------------------------------------------
// qside6 (r5, proven): transposed dd (A=P,B=Q) -> per-lane softmax -> 16x16x16
// PV with register qp handoff. P/CT/kcs staged once per block.
// grid 1024 = 64 bh x 16 tiles (256 rows). 512 thr (8 waves x 2 row-tiles).
// ---------------------------------------------------------------------------
__global__ __launch_bounds__(512, 2) void qside6(const ushort_t* __restrict__ QHL,
                                                 const ushort_t* __restrict__ PHI,
                                                 const ushort_t* __restrict__ PLO,
                                                 const float* __restrict__ DIAGQ,
                                                 const float* __restrict__ kcs,
                                                 const ushort_t* __restrict__ CTH,
                                                 const ushort_t* __restrict__ CTL,
                                                 ushort_t* __restrict__ attb)
{
  extern __shared__ ushort_t lds[];
  ushort_t* pst = lds;            // 32768 ushorts
  ushort_t* ctf = lds + 32768;    // 32768 ushorts
  ushort_t* kcf = lds + 65536;    // 4096 ushorts

  const int tid = threadIdx.x;
  const int l = tid & 63, w = tid >> 6;
  const int ll = l & 15, lh = l >> 4;
  const int bh = blockIdx.x >> 4, qt = blockIdx.x & 15;
  const int b = bh >> 4, h = bh & 15;

  #pragma unroll
  for (int i = 0; i < 8; ++i) {
    const int f = tid + i * 512;
    const int fl = f & 63, r = f >> 6;
    const int p = r & 1, ks = (r >> 1) & 1, mt = r >> 2;
    const ushort_t* src = (p ? PLO : PHI) + (mt * 16 + (fl & 15)) * 64 + ks * 32 + (fl >> 4) * 8;
    *(short8*)&pst[f * 8] = *(const short8*)src;
  }
  #pragma unroll
  for (int i = 0; i < 16; ++i) {
    const int g = tid + i * 512;
    const int gl = g & 63, r = g >> 6;
    const int dt = r & 3, r2 = r >> 2, mt = r2 & 15, p = r2 >> 4;
    const ushort_t* src = (p ? CTL : CTH) +
        ((size_t)bh * 64 + dt * 16 + (gl & 15)) * MF + mt * 16 + (gl >> 4) * 4;
    *(ushort4*)&ctf[g * 4] = *(const ushort4*)src;
  }
  #pragma unroll
  for (int i = 0; i < 2; ++i) {
    const int u = tid + i * 512;
    const int ul = u & 63, mt = u >> 6;
    const int cll = ul & 15, clh = ul >> 4;
    ushort4 o = make_ushort4(0, 0, 0, 0);
    if (cll < 2) {
      #pragma unroll
      for (int e = 0; e < 4; ++e) {
        const float kv = kcs[bh * MF + mt * 16 + clh * 4 + e];
        const unsigned short hi = f2bf(kv);
        ((ushort_t*)&o)[e] = (cll == 0) ? hi : f2bf(kv - bf2f(hi));
      }
    }
    *(ushort4*)&kcf[u * 4] = o;
  }
  __syncthreads();

  const int nloc0 = qt * 256 + w * 32;
  const int rowb0 = b * NSEQ + nloc0;

  short8 qh0[2], ql0[2], qh1[2], ql1[2];
  #pragma unroll
  for (int ks = 0; ks < 2; ++ks) {
    const size_t base = ((size_t)(rowb0 + ll) * 16 + h) * 128 + ks * 32 + lh * 8;
    qh0[ks] = *(const short8*)&QHL[base];
    ql0[ks] = *(const short8*)&QHL[base + 64];
    qh1[ks] = *(const short8*)&QHL[base + (size_t)16 * 2048];
    ql1[ks] = *(const short8*)&QHL[base + (size_t)16 * 2048 + 64];
  }
  const float dg0 = DIAGQ[bh * 4096 + nloc0 + ll];
  const float dg1 = DIAGQ[bh * 4096 + nloc0 + 16 + ll];

  f32x4 dd0[16], dd1[16];
  #pragma unroll
  for (int mt = 0; mt < 16; ++mt) {
    const short8 ph0 = *(const short8*)&pst[((mt * 2 + 0) * 2 + 0) * 512 + l * 8];
    const short8 ph1 = *(const short8*)&pst[((mt * 2 + 1) * 2 + 0) * 512 + l * 8];
    const short8 pl0 = *(const short8*)&pst[((mt * 2 + 0) * 2 + 1) * 512 + l * 8];
    const short8 pl1 = *(const short8*)&pst[((mt * 2 + 1) * 2 + 1) * 512 + l * 8];
    f32x4 a0 = (f32x4){0.f, 0.f, 0.f, 0.f};
    f32x4 a1 = (f32x4){0.f, 0.f, 0.f, 0.f};
    a0 = mfma16(ph0, qh0[0], a0); a0 = mfma16(ph1, qh0[1], a0);
    a0 = mfma16(ph0, ql0[0], a0); a0 = mfma16(ph1, ql0[1], a0);
    a0 = mfma16(pl0, qh0[0], a0); a0 = mfma16(pl1, qh0[1], a0);
    a1 = mfma16(ph0, qh1[0], a1); a1 = mfma16(ph1, qh1[1], a1);
    a1 = mfma16(ph0, ql1[0], a1); a1 = mfma16(ph1, ql1[1], a1);
    a1 = mfma16(pl0, qh1[0], a1); a1 = mfma16(pl1, qh1[1], a1);
    dd0[mt] = a0; dd1[mt] = a1;
  }

  float rm0 = -3.0e38f, rm1 = -3.0e38f;
  #pragma unroll
  for (int mt = 0; mt < 16; ++mt) {
    rm0 = fmaxf(rm0, fmaxf(fmaxf(dd0[mt][0], dd0[mt][1]), fmaxf(dd0[mt][2], dd0[mt][3])));
    rm1 = fmaxf(rm1, fmaxf(fmaxf(dd1[mt][0], dd1[mt][1]), fmaxf(dd1[mt][2], dd1[mt][3])));
  }
  rm0 = fmaxf(rm0, __shfl_xor(rm0, 16, 64)); rm0 = fmaxf(rm0, __shfl_xor(rm0, 32, 64));
  rm1 = fmaxf(rm1, __shfl_xor(rm1, 16, 64)); rm1 = fmaxf(rm1, __shfl_xor(rm1, 32, 64));
  rm0 *= DN; rm1 *= DN;

  short4v qp0[16], qp1[16];
  #pragma unroll
  for (int mt = 0; mt < 16; ++mt) {
    short4v o0, o1;
    #pragma unroll
    for (int jr = 0; jr < 4; ++jr) {
      o0[jr] = (short)f2bf(RATIO * (__expf(dd0[mt][jr] * DN - dg0 - rm0) + EPSF));
      o1[jr] = (short)f2bf(RATIO * (__expf(dd1[mt][jr] * DN - dg1 - rm1) + EPSF));
    }
    qp0[mt] = o0; qp1[mt] = o1;
  }

  f32x4 av0[4], av1[4];
  #pragma unroll
  for (int dt = 0; dt < 4; ++dt) {
    av0[dt] = (f32x4){0.f, 0.f, 0.f, 0.f};
    av1[dt] = (f32x4){0.f, 0.f, 0.f, 0.f};
  }
  f32x4 aK0 = (f32x4){0.f, 0.f, 0.f, 0.f};
  f32x4 aK1 = (f32x4){0.f, 0.f, 0.f, 0.f};
  #pragma unroll
  for (int mt = 0; mt < 16; ++mt) {
    const short4v kcv = *(const short4v*)&kcf[mt * 256 + l * 4];
    aK0 = mfma16x16(qp0[mt], kcv, aK0);
    aK1 = mfma16x16(qp1[mt], kcv, aK1);
    #pragma unroll
    for (int dt = 0; dt < 4; ++dt) {
      const short4v ch = *(const short4v*)&ctf[((0 * 16 + mt) * 4 + dt) * 256 + l * 4];
      const short4v cl = *(const short4v*)&ctf[((16 + mt) * 4 + dt) * 256 + l * 4];
      av0[dt] = mfma16x16(qp0[mt], ch, av0[dt]);
      av0[dt] = mfma16x16(qp0[mt], cl, av0[dt]);
      av1[dt] = mfma16x16(qp1[mt], ch, av1[dt]);
      av1[dt] = mfma16x16(qp1[mt], cl, av1[dt]);
    }
  }

  float di0[4], di1[4];
  #pragma unroll
  for (int jr = 0; jr < 4; ++jr) {
    const float h0 = __shfl(aK0[jr], (l & 48), 64);
    const float l0 = __shfl(aK0[jr], (l & 48) | 1, 64);
    const float h1 = __shfl(aK1[jr], (l & 48), 64);
    const float l1 = __shfl(aK1[jr], (l & 48) | 1, 64);
    di0[jr] = 1.0f / (h0 + l0);
    di1[jr] = 1.0f / (h1 + l1);
  }

  #pragma unroll
  for (int dt = 0; dt < 4; ++dt)
    #pragma unroll
    for (int jr = 0; jr < 4; ++jr) {
      const int col = h * DHD + dt * 16 + ll;
      attb[(size_t)(rowb0 + lh * 4 + jr) * DM + col] = f2bf(av0[dt][jr] * di0[jr]);
      attb[(size_t)(rowb0 + 16 + lh * 4 + jr) * DM + col] = f2bf(av1[dt][jr] * di1[jr]);
    }
}

// ---------------------------------------------------------------------------
extern "C" void kernel_launch(void* const* d_in, const int* in_sizes, int n_in,
                              void* d_out, int out_size, void* d_ws, size_t ws_size,
                              hipStream_t stream)
{
  const float* x  = (const float*)d_in[0];
  const float* Wq = (const float*)d_in[1];
  const float* Wk = (const float*)d_in[2];
  const float* Wv = (const float*)d_in[3];
  const float* Wo = (const float*)d_in[4];
  const float* bo = (const float*)d_in[5];
  const float* P  = (const float*)d_in[6];
  float* out = (float*)d_out;

  char* wp = (char*)d_ws;
  ushort_t* QHL   = (ushort_t*)(wp + 0);            // 64 MB [row][h][128]
  ushort_t* KHL   = (ushort_t*)(wp + 67108864);     // 64 MB (ATTB overlays)
  ushort_t* VT    = (ushort_t*)(wp + 134217728);    // 32 MB [bh][dh][n]
  ushort_t* Wqt   = (ushort_t*)(wp + 167772160);
  ushort_t* Wkt   = (ushort_t*)(wp + 169869312);
  ushort_t* Wvt   = (ushort_t*)(wp + 171966464);
  ushort_t* Wot   = (ushort_t*)(wp + 174063616);
  ushort_t* PHI   = (ushort_t*)(wp + 176160768);
  ushort_t* PLO   = (ushort_t*)(wp + 176193536);
  float*    DIAGQ = (float*)(wp + 176226304);       // 1 MB
  float*    DIAGK = (float*)(wp + 177274880);       // 1 MB
  float*    PARTK = (float*)(wp + 178323456);       // 512 KB
  float*    MW    = (float*)(wp + 178847744);       // 8 KB
  float*    VSUM  = (float*)(wp + 178855936);       // 16 KB
  unsigned* MX    = (unsigned*)(wp + 178872320);    // 256 B (contiguous w/ VSUM)
  float*    KCS   = (float*)(wp + 178872576);       // 64 KB
  ushort_t* CTH   = (ushort_t*)(wp + 178938112);    // 2 MB
  ushort_t* CTL   = (ushort_t*)(wp + 181035264);    // 2 MB -> end 183132416
  ushort_t* ATTB  = KHL;

  // scratch carved out of d_out (fully overwritten by the final Wo-GEMM):
  float*    PARTC = (float*)d_out;                           // 32 MB
  ushort_t* XB    = (ushort_t*)((char*)d_out + 33554432);    // 32 MB

  dim3 tg(16, 16);
  wtrans<<<tg, 256, 0, stream>>>(Wq, Wqt);
  wtrans<<<tg, 256, 0, stream>>>(Wk, Wkt);
  wtrans<<<tg, 256, 0, stream>>>(Wv, Wvt);
  wtrans<<<tg, 256, 0, stream>>>(Wo, Wot);
  psplit<<<64, 256, 0, stream>>>(P, PHI, PLO);
  xconv<<<8192, 256, 0, stream>>>(x, XB);
  hipMemsetAsync(VSUM, 0, 16384 + 256, stream);   // VSUM + MX

  gemm_k<3><<<1024, 256, 0, stream>>>(XB, Wqt, nullptr, nullptr, nullptr, QHL, DIAGQ);
  gemm_k<3><<<1024, 256, 0, stream>>>(XB, Wkt, nullptr, nullptr, nullptr, KHL, DIAGK);
  gemm_k<2><<<1024, 256, 0, stream>>>(XB, Wvt, nullptr, nullptr, VT, nullptr, nullptr);

  kside5w<<<512, 256, 0, stream>>>(KHL, VT, PHI, PLO, DIAGK, PARTC, PARTK, MW, VSUM, MX);
  combine<<<256, 256, 0, stream>>>(PARTC, PARTK, MW, VSUM, MX, KCS, CTH, CTL);
  qside6<<<1024, 512, 139264, stream>>>(QHL, PHI, PLO, DIAGQ, KCS, CTH, CTL, ATTB);

  gemm_k<1><<<1024, 256, 0, stream>>>(ATTB, Wot, bo, out, nullptr, nullptr, nullptr);
}

// Round 11
// 428.616 us; speedup vs baseline: 1.2260x; 1.0519x over previous
//
#include <hip/hip_runtime.h>
#include <math.h>

#define NB 4
#define NSEQ 4096
#define DM 1024
#define NHEAD 16
#define DHD 64
#define MF 256
#define ROWS 16384

#define DN 0.35355339059327373f
#define RATIO 0.0625f
#define HALF_DN2 0.0625f
#define EPSF 1.0e-4f
#define THR_DEFER 4.0f

typedef __attribute__((ext_vector_type(4))) float f32x4;
typedef __attribute__((ext_vector_type(8))) short short8;
typedef __attribute__((ext_vector_type(4))) short short4v;
typedef __attribute__((ext_vector_type(8))) __bf16 bf16x8;
typedef unsigned short ushort_t;

__device__ __forceinline__ unsigned short f2bf(float f) {
  unsigned int u = __builtin_bit_cast(unsigned int, f);
  u += 0x7FFFu + ((u >> 16) & 1u);
  return (unsigned short)(u >> 16);
}
__device__ __forceinline__ float bf2f(unsigned short h) {
  unsigned int u = ((unsigned int)h) << 16;
  return __builtin_bit_cast(float, u);
}

__device__ __forceinline__ f32x4 mfma16(short8 a, short8 b, f32x4 c) {
  return __builtin_amdgcn_mfma_f32_16x16x32_bf16(
      __builtin_bit_cast(bf16x8, a), __builtin_bit_cast(bf16x8, b), c, 0, 0, 0);
}

// 16x16x16 bf16 MFMA (K=16). Fragment mappings validated end-to-end in r4/r5.
__device__ __forceinline__ f32x4 mfma16x16(short4v a, short4v b, f32x4 c) {
#if __has_builtin(__builtin_amdgcn_mfma_f32_16x16x16bf16_1k)
  return __builtin_amdgcn_mfma_f32_16x16x16bf16_1k(a, b, c, 0, 0, 0);
#elif __has_builtin(__builtin_amdgcn_mfma_f32_16x16x16_bf16)
  typedef __attribute__((ext_vector_type(4))) __bf16 bf16x4;
  return __builtin_amdgcn_mfma_f32_16x16x16_bf16(
      __builtin_bit_cast(bf16x4, a), __builtin_bit_cast(bf16x4, b), c, 0, 0, 0);
#else
  asm volatile("s_nop 1\n\t"
               "v_mfma_f32_16x16x16_bf16 %0, %1, %2, %0\n\t"
               "s_nop 7"
               : "+v"(c) : "v"(a), "v"(b));
  return c;
#endif
}

__device__ __forceinline__ void glds16(const void* g, void* l) {
  __builtin_amdgcn_global_load_lds(
      (const __attribute__((address_space(1))) unsigned int*)g,
      (__attribute__((address_space(3))) unsigned int*)l, 16, 0, 0);
}

// ---------------------------------------------------------------------------
// Weight transpose-cast: Wt[n][k] = bf16(W[k][n]).
// ---------------------------------------------------------------------------
__global__ __launch_bounds__(256) void wtrans(const float* __restrict__ W,
                                              ushort_t* __restrict__ Wt)
{
  __shared__ float ts[64][68];
  const int tid = threadIdx.x;
  const int k0 = blockIdx.y * 64, n0 = blockIdx.x * 64;
  const int r = tid >> 4, c4 = (tid & 15) * 4;
  #pragma unroll
  for (int i = 0; i < 4; ++i) {
    float4 v = *(const float4*)&W[(size_t)(k0 + r + i * 16) * DM + n0 + c4];
    *(float4*)&ts[r + i * 16][c4] = v;
  }
  __syncthreads();
  #pragma unroll
  for (int i = 0; i < 4; ++i) {
    const int n = r + i * 16;
    ushort4 o;
    o.x = f2bf(ts[c4 + 0][n]); o.y = f2bf(ts[c4 + 1][n]);
    o.z = f2bf(ts[c4 + 2][n]); o.w = f2bf(ts[c4 + 3][n]);
    *(ushort4*)&Wt[(size_t)(n0 + n) * DM + k0 + c4] = o;
  }
}

// ---------------------------------------------------------------------------
__global__ __launch_bounds__(256) void psplit(const float* __restrict__ P,
                                              ushort_t* __restrict__ PHI,
                                              ushort_t* __restrict__ PLO)
{
  const int i = blockIdx.x * 256 + threadIdx.x;
  const float v = P[i];
  const unsigned short h = f2bf(v);
  PHI[i] = h;
  PLO[i] = f2bf(v - bf2f(h));
}

// ---------------------------------------------------------------------------
__global__ __launch_bounds__(256) void xconv(const float* __restrict__ x,
                                             ushort_t* __restrict__ xb)
{
  const size_t i = ((size_t)blockIdx.x * 256 + threadIdx.x) * 8;
  const float4 a = *(const float4*)&x[i];
  const float4 c = *(const float4*)&x[i + 4];
  short8 o;
  o[0] = f2bf(a.x); o[1] = f2bf(a.y); o[2] = f2bf(a.z); o[3] = f2bf(a.w);
  o[4] = f2bf(c.x); o[5] = f2bf(c.y); o[6] = f2bf(c.z); o[7] = f2bf(c.w);
  *(short8*)&xb[i] = o;
}

// ---------------------------------------------------------------------------
// Merged QKV GEMM: [Q|K|V][16384,3072] = XB[16384,1024] @ Wt[3072,1024]^T.
// 128x128 tile, BK=32, grid 3072. Region (by col block) selects epilogue:
//   cols [0,1024)    -> QHL hi|lo + DIAGQ      (EPI3)
//   cols [1024,2048) -> KHL hi|lo + DIAGK      (EPI3)
//   cols [2048,3072) -> VT bf16 [bh][dh][n]    (EPI2)
// Swizzle: XCD gets bn-fastest contiguous range -> A working set ~4MB = L2.
// ---------------------------------------------------------------------------
__global__ __launch_bounds__(256) void gemm_qkv(const ushort_t* __restrict__ Ab,
                                                const ushort_t* __restrict__ Bt,
                                                ushort_t* __restrict__ QHL,
                                                ushort_t* __restrict__ KHL,
                                                ushort_t* __restrict__ VT,
                                                float* __restrict__ DIAGQ,
                                                float* __restrict__ DIAGK)
{
  constexpr int K = DM;
  __shared__ ushort_t As[128 * 32];
  __shared__ ushort_t Bs[128 * 32];

  const int tid = threadIdx.x;
  const int l = tid & 63, w = tid >> 6;
  const int ll = l & 15, lh = l >> 4;
  const int wr = w >> 1, wc = w & 1;

  const int bid = blockIdx.x;
  const int swz = (bid & 7) * 384 + (bid >> 3);
  const int bm = swz / 24, bn = swz % 24;
  const int row0 = bm * 128, col0 = bn * 128;

  const int pb0 = w * 128 + l, pb1 = pb0 + 64;
  const int brow0 = pb0 >> 2, bkq0 = (pb0 & 3) ^ ((brow0 >> 1) & 3);
  const int brow1 = pb1 >> 2, bkq1 = (pb1 & 3) ^ ((brow1 >> 1) & 3);
  const ushort_t* bsrc0 = Bt + (size_t)(col0 + brow0) * K + bkq0 * 8;
  const ushort_t* bsrc1 = Bt + (size_t)(col0 + brow1) * K + bkq1 * 8;
  ushort_t* bdst0 = &Bs[(size_t)(w * 128) * 8];
  ushort_t* bdst1 = &Bs[(size_t)(w * 128 + 64) * 8];

  const ushort_t* asrc0 = Ab + (size_t)(row0 + brow0) * K + bkq0 * 8;
  const ushort_t* asrc1 = Ab + (size_t)(row0 + brow1) * K + bkq1 * 8;

  int aoff[4], boff[4];
  #pragma unroll
  for (int mt = 0; mt < 4; ++mt) {
    const int r = wr * 64 + mt * 16 + ll;
    aoff[mt] = (r * 4 + (lh ^ ((r >> 1) & 3))) * 8;
  }
  #pragma unroll
  for (int nt = 0; nt < 4; ++nt) {
    const int r = wc * 64 + nt * 16 + ll;
    boff[nt] = (r * 4 + (lh ^ ((r >> 1) & 3))) * 8;
  }

  f32x4 acc[4][4];
  #pragma unroll
  for (int i = 0; i < 4; ++i)
    #pragma unroll
    for (int j = 0; j < 4; ++j) acc[i][j] = (f32x4){0.f, 0.f, 0.f, 0.f};

  for (int k0 = 0; k0 < K; k0 += 32) {
    __syncthreads();
    glds16(asrc0 + k0, &As[(size_t)(w * 128) * 8]);
    glds16(asrc1 + k0, &As[(size_t)(w * 128 + 64) * 8]);
    glds16(bsrc0 + k0, bdst0);
    glds16(bsrc1 + k0, bdst1);
    __syncthreads();

    short8 av[4], bv[4];
    #pragma unroll
    for (int mt = 0; mt < 4; ++mt) av[mt] = *(const short8*)&As[aoff[mt]];
    #pragma unroll
    for (int nt = 0; nt < 4; ++nt) bv[nt] = *(const short8*)&Bs[boff[nt]];
    #pragma unroll
    for (int mt = 0; mt < 4; ++mt)
      #pragma unroll
      for (int nt = 0; nt < 4; ++nt)
        acc[mt][nt] = mfma16(av[mt], bv[nt], acc[mt][nt]);
  }

  const int region = col0 >> 10;     // 0=Q, 1=K, 2=V  (uniform per block)
  const int lc0 = col0 & 1023;
  if (region == 2) {
    // EPI2: VT bf16 [bh][dh][n]
    #pragma unroll
    for (int mt = 0; mt < 4; ++mt) {
      #pragma unroll
      for (int nt = 0; nt < 4; ++nt) {
        const int rg = row0 + wr * 64 + mt * 16 + lh * 4;
        const int cg = lc0 + wc * 64 + nt * 16 + ll;
        const int b = rg >> 12, n = rg & 4095;
        const int h = cg >> 6, dh = cg & 63;
        ushort4 o;
        o.x = f2bf(acc[mt][nt][0]); o.y = f2bf(acc[mt][nt][1]);
        o.z = f2bf(acc[mt][nt][2]); o.w = f2bf(acc[mt][nt][3]);
        *(ushort4*)&VT[(((size_t)b * 16 + h) * 64 + dh) * 4096 + n] = o;
      }
    }
  } else {
    // EPI3: hi|lo [row][h][128] + diag
    ushort_t* OHL = region ? KHL : QHL;
    float* DIAG = region ? DIAGK : DIAGQ;
    const int hglob = (lc0 >> 6) + wc;
    #pragma unroll
    for (int mt = 0; mt < 4; ++mt) {
      float rssq[4] = {0.f, 0.f, 0.f, 0.f};
      #pragma unroll
      for (int nt = 0; nt < 4; ++nt) {
        const int row = row0 + wr * 64 + mt * 16 + lh * 4;
        const int e = nt * 16 + ll;
        #pragma unroll
        for (int j = 0; j < 4; ++j) {
          const float v = acc[mt][nt][j];
          rssq[j] += v * v;
          const unsigned short hh = f2bf(v);
          const size_t base = ((size_t)(row + j) * 16 + hglob) * 128 + e;
          OHL[base] = hh;
          OHL[base + 64] = f2bf(v - bf2f(hh));
        }
      }
      #pragma unroll
      for (int j = 0; j < 4; ++j) {
        float s = rssq[j];
        s += __shfl_xor(s, 1, 64); s += __shfl_xor(s, 2, 64);
        s += __shfl_xor(s, 4, 64); s += __shfl_xor(s, 8, 64);
        if (ll == 0) {
          const int row = row0 + wr * 64 + mt * 16 + lh * 4 + j;
          DIAG[(((row >> 12) * 16 + hglob) << 12) + (row & 4095)] = HALF_DN2 * s;
        }
      }
    }
  }
}

// ---------------------------------------------------------------------------
// Wo GEMM: C[16384,1024] = ATT @ Wot^T + bias. (r5 gemm_k EPI=1, unchanged)
// ---------------------------------------------------------------------------
__global__ __launch_bounds__(256) void gemm_wo(const ushort_t* __restrict__ Ab,
                                               const ushort_t* __restrict__ Bt,
                                               const float* __restrict__ bias,
                                               float* __restrict__ C)
{
  constexpr int K = DM, N = DM;
  __shared__ ushort_t As[128 * 32];
  __shared__ ushort_t Bs[128 * 32];

  const int tid = threadIdx.x;
  const int l = tid & 63, w = tid >> 6;
  const int ll = l & 15, lh = l >> 4;
  const int wr = w >> 1, wc = w & 1;

  const int bid = blockIdx.x;
  const int swz = (bid & 7) * ((int)gridDim.x >> 3) + (bid >> 3);
  const int bm = swz >> 3, bn = swz & 7;
  const int row0 = bm * 128, col0 = bn * 128;

  const int pb0 = w * 128 + l, pb1 = pb0 + 64;
  const int brow0 = pb0 >> 2, bkq0 = (pb0 & 3) ^ ((brow0 >> 1) & 3);
  const int brow1 = pb1 >> 2, bkq1 = (pb1 & 3) ^ ((brow1 >> 1) & 3);
  const ushort_t* bsrc0 = Bt + (size_t)(col0 + brow0) * K + bkq0 * 8;
  const ushort_t* bsrc1 = Bt + (size_t)(col0 + brow1) * K + bkq1 * 8;
  ushort_t* bdst0 = &Bs[(size_t)(w * 128) * 8];
  ushort_t* bdst1 = &Bs[(size_t)(w * 128 + 64) * 8];

  const ushort_t* asrc0 = Ab + (size_t)(row0 + brow0) * K + bkq0 * 8;
  const ushort_t* asrc1 = Ab + (size_t)(row0 + brow1) * K + bkq1 * 8;

  int aoff[4], boff[4];
  #pragma unroll
  for (int mt = 0; mt < 4; ++mt) {
    const int r = wr * 64 + mt * 16 + ll;
    aoff[mt] = (r * 4 + (lh ^ ((r >> 1) & 3))) * 8;
  }
  #pragma unroll
  for (int nt = 0; nt < 4; ++nt) {
    const int r = wc * 64 + nt * 16 + ll;
    boff[nt] = (r * 4 + (lh ^ ((r >> 1) & 3))) * 8;
  }

  f32x4 acc[4][4];
  #pragma unroll
  for (int i = 0; i < 4; ++i)
    #pragma unroll
    for (int j = 0; j < 4; ++j) acc[i][j] = (f32x4){0.f, 0.f, 0.f, 0.f};

  for (int k0 = 0; k0 < K; k0 += 32) {
    __syncthreads();
    glds16(asrc0 + k0, &As[(size_t)(w * 128) * 8]);
    glds16(asrc1 + k0, &As[(size_t)(w * 128 + 64) * 8]);
    glds16(bsrc0 + k0, bdst0);
    glds16(bsrc1 + k0, bdst1);
    __syncthreads();

    short8 av[4], bv[4];
    #pragma unroll
    for (int mt = 0; mt < 4; ++mt) av[mt] = *(const short8*)&As[aoff[mt]];
    #pragma unroll
    for (int nt = 0; nt < 4; ++nt) bv[nt] = *(const short8*)&Bs[boff[nt]];
    #pragma unroll
    for (int mt = 0; mt < 4; ++mt)
      #pragma unroll
      for (int nt = 0; nt < 4; ++nt)
        acc[mt][nt] = mfma16(av[mt], bv[nt], acc[mt][nt]);
  }

  #pragma unroll
  for (int mt = 0; mt < 4; ++mt) {
    #pragma unroll
    for (int nt = 0; nt < 4; ++nt) {
      const int row = row0 + wr * 64 + mt * 16 + lh * 4;
      const int col = col0 + wc * 64 + nt * 16 + ll;
      const float bv_ = bias[col];
      #pragma unroll
      for (int j = 0; j < 4; ++j)
        C[(size_t)(row + j) * N + col] = acc[mt][nt][j] + bv_;
    }
  }
}

// ---------------------------------------------------------------------------
// kside5 (r5-exact, proven 91 us): single-pass online-max K-side.
// grid 512 = 64 bh x 8 chunks (512 rows), 256 thr = 4 waves x 64 m.
// ---------------------------------------------------------------------------
__global__ __launch_bounds__(256) void kside5(const ushort_t* __restrict__ KHL,
                                              const ushort_t* __restrict__ VT,
                                              const ushort_t* __restrict__ PHI,
                                              const ushort_t* __restrict__ PLO,
                                              const float* __restrict__ DIAGK,
                                              float* __restrict__ partC,
                                              float* __restrict__ partK,
                                              float* __restrict__ mw,
                                              float* __restrict__ vsum,
                                              unsigned* __restrict__ mxp)
{
  const int tid = threadIdx.x;
  const int l = tid & 63, mg = tid >> 6;
  const int ll = l & 15, lh = l >> 4;
  const int blk = blockIdx.x;
  const int bh = blk >> 3, ck = blk & 7;
  const int b = bh >> 4, h = bh & 15;

  short8 pfh[4][2], pfl[4][2];
  #pragma unroll
  for (int mt = 0; mt < 4; ++mt)
    #pragma unroll
    for (int ks = 0; ks < 2; ++ks) {
      const size_t off = (size_t)(mg * 64 + mt * 16 + ll) * 64 + ks * 32 + lh * 8;
      pfh[mt][ks] = *(const short8*)&PHI[off];
      pfl[mt][ks] = *(const short8*)&PLO[off];
    }

  f32x4 apv[4][4];
  #pragma unroll
  for (int i = 0; i < 4; ++i)
    #pragma unroll
    for (int j = 0; j < 4; ++j) apv[i][j] = (f32x4){0.f, 0.f, 0.f, 0.f};
  float kcp[4] = {0.f, 0.f, 0.f, 0.f};
  float vs[4] = {0.f, 0.f, 0.f, 0.f};
  float m_run = -1.0e30f, tmax = -1.0e30f;

  const int n0 = ck * 512;
  const ushort_t* krow = KHL + ((size_t)(b * NSEQ + n0 + ll) * 16 + h) * 128 + lh * 8;
  const ushort_t* vrow = VT + (size_t)bh * 64 * NSEQ + n0 + lh * 4;
  const float* drow = DIAGK + bh * 4096 + n0 + lh * 4;

  short8 kh0 = *(const short8*)(krow);
  short8 kh1 = *(const short8*)(krow + 32);
  short8 kl0 = *(const short8*)(krow + 64);
  short8 kl1 = *(const short8*)(krow + 96);

  for (int it = 0; it < 32; ++it) {
    short8 nh0, nh1, nl0, nl1;
    if (it < 31) {
      const ushort_t* kp = krow + (size_t)(it + 1) * 16 * 2048;
      nh0 = *(const short8*)(kp);
      nh1 = *(const short8*)(kp + 32);
      nl0 = *(const short8*)(kp + 64);
      nl1 = *(const short8*)(kp + 96);
    }
    const float4 dg4 = *(const float4*)(drow + it * 16);
    short4v vf[4];
    #pragma unroll
    for (int dt = 0; dt < 4; ++dt)
      vf[dt] = *(const short4v*)&vrow[(size_t)(dt * 16 + ll) * NSEQ + it * 16];

    f32x4 dda[4];
    #pragma unroll
    for (int mt = 0; mt < 4; ++mt) {
      f32x4 acc = (f32x4){0.f, 0.f, 0.f, 0.f};
      acc = mfma16(kh0, pfh[mt][0], acc); acc = mfma16(kh1, pfh[mt][1], acc);
      acc = mfma16(kh0, pfl[mt][0], acc); acc = mfma16(kh1, pfl[mt][1], acc);
      acc = mfma16(kl0, pfh[mt][0], acc); acc = mfma16(kl1, pfh[mt][1], acc);
      #pragma unroll
      for (int jr = 0; jr < 4; ++jr) acc[jr] *= DN;
      dda[mt] = acc;
    }

    float pm = -1.0e30f;
    #pragma unroll
    for (int mt = 0; mt < 4; ++mt)
      #pragma unroll
      for (int jr = 0; jr < 4; ++jr) pm = fmaxf(pm, dda[mt][jr]);
    tmax = fmaxf(tmax, pm);
    if (!__all(pm <= m_run + THR_DEFER)) {
      float pw = pm;
      pw = fmaxf(pw, m_run);
      pw = fmaxf(pw, __shfl_xor(pw, 1, 64));  pw = fmaxf(pw, __shfl_xor(pw, 2, 64));
      pw = fmaxf(pw, __shfl_xor(pw, 4, 64));  pw = fmaxf(pw, __shfl_xor(pw, 8, 64));
      pw = fmaxf(pw, __shfl_xor(pw, 16, 64)); pw = fmaxf(pw, __shfl_xor(pw, 32, 64));
      const float sc = __expf(m_run - pw);
      #pragma unroll
      for (int mt = 0; mt < 4; ++mt) {
        kcp[mt] *= sc;
        #pragma unroll
        for (int dt = 0; dt < 4; ++dt) apv[mt][dt] *= sc;
      }
      m_run = pw;
    }

    const float dgv[4] = {dg4.x, dg4.y, dg4.z, dg4.w};
    short4v qa[4];
    #pragma unroll
    for (int mt = 0; mt < 4; ++mt) {
      short4v o;
      float s = 0.f;
      #pragma unroll
      for (int jr = 0; jr < 4; ++jr) {
        const float kv = __expf(dda[mt][jr] - dgv[jr] - m_run);
        const unsigned short ub = f2bf(kv);
        o[jr] = (short)ub;
        s += bf2f(ub);
      }
      qa[mt] = o;
      kcp[mt] += s;
    }

    if (mg == 0) {
      #pragma unroll
      for (int dt = 0; dt < 4; ++dt)
        #pragma unroll
        for (int e = 0; e < 4; ++e) vs[dt] += bf2f((ushort_t)vf[dt][e]);
    }

    #pragma unroll
    for (int dt = 0; dt < 4; ++dt)
      #pragma unroll
      for (int mt = 0; mt < 4; ++mt)
        apv[mt][dt] = mfma16x16(qa[mt], vf[dt], apv[mt][dt]);

    kh0 = nh0; kh1 = nh1; kl0 = nl0; kl1 = nl1;
  }

  // epilogue
  #pragma unroll
  for (int mt = 0; mt < 4; ++mt) {
    float s = kcp[mt];
    s += __shfl_xor(s, 16, 64);
    s += __shfl_xor(s, 32, 64);
    if (lh == 0) partK[blk * 256 + mg * 64 + mt * 16 + ll] = s;
  }
  #pragma unroll
  for (int mt = 0; mt < 4; ++mt)
    #pragma unroll
    for (int dt = 0; dt < 4; ++dt)
      #pragma unroll
      for (int jr = 0; jr < 4; ++jr) {
        const int m = mg * 64 + mt * 16 + lh * 4 + jr;
        const int dh = dt * 16 + ll;
        partC[(size_t)blk * 16384 + (size_t)m * 64 + dh] = apv[mt][dt][jr];
      }
  if (mg == 0) {
    #pragma unroll
    for (int dt = 0; dt < 4; ++dt) {
      float s = vs[dt];
      s += __shfl_xor(s, 16, 64);
      s += __shfl_xor(s, 32, 64);
      if (lh == 0) atomicAdd(&vsum[bh * 64 + dt * 16 + ll], s);
    }
  }
  tmax = fmaxf(tmax, __shfl_xor(tmax, 1, 64));  tmax = fmaxf(tmax, __shfl_xor(tmax, 2, 64));
  tmax = fmaxf(tmax, __shfl_xor(tmax, 4, 64));  tmax = fmaxf(tmax, __shfl_xor(tmax, 8, 64));
  tmax = fmaxf(tmax, __shfl_xor(tmax, 16, 64)); tmax = fmaxf(tmax, __shfl_xor(tmax, 32, 64));
  if (l == 0) {
    atomicMax(mxp, __float_as_uint(tmax));
    mw[blk * 4 + mg] = m_run;
  }
}

// ---------------------------------------------------------------------------
// combine (r5-exact): fold 8 partials/bh -> KCS fp32 + CTH/CTL [bh][dh][m].
// grid 256 = 64 bh x 4 m-chunks.
// ---------------------------------------------------------------------------
__global__ __launch_bounds__(256) void combine(const float* __restrict__ partC,
                                               const float* __restrict__ partK,
                                               const float* __restrict__ mw,
                                               const float* __restrict__ vsum,
                                               const unsigned* __restrict__ mxp,
                                               float* __restrict__ KCS,
                                               ushort_t* __restrict__ CTH,
                                               ushort_t* __restrict__ CTL)
{
  const int tid = threadIdx.x;
  const int bh = blockIdx.x >> 2, mc = blockIdx.x & 3;
  const float MX = __uint_as_float(*mxp);
  float s[8];
  #pragma unroll
  for (int c = 0; c < 8; ++c)
    s[c] = RATIO * __expf(mw[(bh * 8 + c) * 4 + mc] - MX);

  __shared__ float ts[64][68];
  const int r = tid >> 4, c4 = (tid & 15) * 4;
  const float reps = RATIO * EPSF;
  const float4 v4 = *(const float4*)&vsum[bh * 64 + c4];
  #pragma unroll
  for (int i = 0; i < 4; ++i) {
    const int ml = r + i * 16;
    float4 a;
    a.x = reps * v4.x; a.y = reps * v4.y; a.z = reps * v4.z; a.w = reps * v4.w;
    #pragma unroll
    for (int c = 0; c < 8; ++c) {
      const float4 p = *(const float4*)&partC[(size_t)(bh * 8 + c) * 16384 +
                                              (size_t)(mc * 64 + ml) * 64 + c4];
      a.x += s[c] * p.x; a.y += s[c] * p.y; a.z += s[c] * p.z; a.w += s[c] * p.w;
    }
    *(float4*)&ts[ml][c4] = a;
  }
  if (tid < 64) {
    const int m = mc * 64 + tid;
    float kv = reps * 4096.0f;
    #pragma unroll
    for (int c = 0; c < 8; ++c) kv += s[c] * partK[(bh * 8 + c) * 256 + m];
    KCS[bh * 256 + m] = kv;
  }
  __syncthreads();
  #pragma unroll
  for (int i = 0; i < 4; ++i) {
    const int dh = r + i * 16;
    ushort4 oh, ol;
    #pragma unroll
    for (int k = 0; k < 4; ++k) {
      const float v = ts[c4 + k][dh];
      const unsigned short hh = f2bf(v);
      ((unsigned short*)&oh)[k] = hh;
      ((unsigned short*)&ol)[k] = f2bf(v - bf2f(hh));
    }
    const size_t o = ((size_t)bh * 64 + dh) * MF + mc * 64 + c4;
    *(ushort4*)&CTH[o] = oh;
    *(ushort4*)&CTL[o] = ol;
  }
}

// ---------------------------------------------------------------------------
// qside6 (r5-exact): transposed dd (A=P,B=Q) -> per-lane softmax -> 16x16x16
// PV with register qp handoff. P/CT/kcs staged once per block.
// grid 1024 = 64 bh x 16 tiles (256 rows). 512 thr (8 waves x 2 row-tiles).
// ---------------------------------------------------------------------------
__global__ __launch_bounds__(512, 2) void qside6(const ushort_t* __restrict__ QHL,
                                                 const ushort_t* __restrict__ PHI,
                                                 const ushort_t* __restrict__ PLO,
                                                 const float* __restrict__ DIAGQ,
                                                 const float* __restrict__ kcs,
                                                 const ushort_t* __restrict__ CTH,
                                                 const ushort_t* __restrict__ CTL,
                                                 ushort_t* __restrict__ attb)
{
  extern __shared__ ushort_t lds[];
  ushort_t* pst = lds;            // 32768 ushorts
  ushort_t* ctf = lds + 32768;    // 32768 ushorts
  ushort_t* kcf = lds + 65536;    // 4096 ushorts

  const int tid = threadIdx.x;
  const int l = tid & 63, w = tid >> 6;
  const int ll = l & 15, lh = l >> 4;
  const int bh = blockIdx.x >> 4, qt = blockIdx.x & 15;
  const int b = bh >> 4, h = bh & 15;

  #pragma unroll
  for (int i = 0; i < 8; ++i) {
    const int f = tid + i * 512;
    const int fl = f & 63, r = f >> 6;
    const int p = r & 1, ks = (r >> 1) & 1, mt = r >> 2;
    const ushort_t* src = (p ? PLO : PHI) + (mt * 16 + (fl & 15)) * 64 + ks * 32 + (fl >> 4) * 8;
    *(short8*)&pst[f * 8] = *(const short8*)src;
  }
  #pragma unroll
  for (int i = 0; i < 16; ++i) {
    const int g = tid + i * 512;
    const int gl = g & 63, r = g >> 6;
    const int dt = r & 3, r2 = r >> 2, mt = r2 & 15, p = r2 >> 4;
    const ushort_t* src = (p ? CTL : CTH) +
        ((size_t)bh * 64 + dt * 16 + (gl & 15)) * MF + mt * 16 + (gl >> 4) * 4;
    *(ushort4*)&ctf[g * 4] = *(const ushort4*)src;
  }
  #pragma unroll
  for (int i = 0; i < 2; ++i) {
    const int u = tid + i * 512;
    const int ul = u & 63, mt = u >> 6;
    const int cll = ul & 15, clh = ul >> 4;
    ushort4 o = make_ushort4(0, 0, 0, 0);
    if (cll < 2) {
      #pragma unroll
      for (int e = 0; e < 4; ++e) {
        const float kv = kcs[bh * MF + mt * 16 + clh * 4 + e];
        const unsigned short hi = f2bf(kv);
        ((ushort_t*)&o)[e] = (cll == 0) ? hi : f2bf(kv - bf2f(hi));
      }
    }
    *(ushort4*)&kcf[u * 4] = o;
  }
  __syncthreads();

  const int nloc0 = qt * 256 + w * 32;
  const int rowb0 = b * NSEQ + nloc0;

  short8 qh0[2], ql0[2], qh1[2], ql1[2];
  #pragma unroll
  for (int ks = 0; ks < 2; ++ks) {
    const size_t base = ((size_t)(rowb0 + ll) * 16 + h) * 128 + ks * 32 + lh * 8;
    qh0[ks] = *(const short8*)&QHL[base];
    ql0[ks] = *(const short8*)&QHL[base + 64];
    qh1[ks] = *(const short8*)&QHL[base + (size_t)16 * 2048];
    ql1[ks] = *(const short8*)&QHL[base + (size_t)16 * 2048 + 64];
  }
  const float dg0 = DIAGQ[bh * 4096 + nloc0 + ll];
  const float dg1 = DIAGQ[bh * 4096 + nloc0 + 16 + ll];

  f32x4 dd0[16], dd1[16];
  #pragma unroll
  for (int mt = 0; mt < 16; ++mt) {
    const short8 ph0 = *(const short8*)&pst[((mt * 2 + 0) * 2 + 0) * 512 + l * 8];
    const short8 ph1 = *(const short8*)&pst[((mt * 2 + 1) * 2 + 0) * 512 + l * 8];
    const short8 pl0 = *(const short8*)&pst[((mt * 2 + 0) * 2 + 1) * 512 + l * 8];
    const short8 pl1 = *(const short8*)&pst[((mt * 2 + 1) * 2 + 1) * 512 + l * 8];
    f32x4 a0 = (f32x4){0.f, 0.f, 0.f, 0.f};
    f32x4 a1 = (f32x4){0.f, 0.f, 0.f, 0.f};
    a0 = mfma16(ph0, qh0[0], a0); a0 = mfma16(ph1, qh0[1], a0);
    a0 = mfma16(ph0, ql0[0], a0); a0 = mfma16(ph1, ql0[1], a0);
    a0 = mfma16(pl0, qh0[0], a0); a0 = mfma16(pl1, qh0[1], a0);
    a1 = mfma16(ph0, qh1[0], a1); a1 = mfma16(ph1, qh1[1], a1);
    a1 = mfma16(ph0, ql1[0], a1); a1 = mfma16(ph1, ql1[1], a1);
    a1 = mfma16(pl0, qh1[0], a1); a1 = mfma16(pl1, qh1[1], a1);
    dd0[mt] = a0; dd1[mt] = a1;
  }

  float rm0 = -3.0e38f, rm1 = -3.0e38f;
  #pragma unroll
  for (int mt = 0; mt < 16; ++mt) {
    rm0 = fmaxf(rm0, fmaxf(fmaxf(dd0[mt][0], dd0[mt][1]), fmaxf(dd0[mt][2], dd0[mt][3])));
    rm1 = fmaxf(rm1, fmaxf(fmaxf(dd1[mt][0], dd1[mt][1]), fmaxf(dd1[mt][2], dd1[mt][3])));
  }
  rm0 = fmaxf(rm0, __shfl_xor(rm0, 16, 64)); rm0 = fmaxf(rm0, __shfl_xor(rm0, 32, 64));
  rm1 = fmaxf(rm1, __shfl_xor(rm1, 16, 64)); rm1 = fmaxf(rm1, __shfl_xor(rm1, 32, 64));
  rm0 *= DN; rm1 *= DN;

  short4v qp0[16], qp1[16];
  #pragma unroll
  for (int mt = 0; mt < 16; ++mt) {
    short4v o0, o1;
    #pragma unroll
    for (int jr = 0; jr < 4; ++jr) {
      o0[jr] = (short)f2bf(RATIO * (__expf(dd0[mt][jr] * DN - dg0 - rm0) + EPSF));
      o1[jr] = (short)f2bf(RATIO * (__expf(dd1[mt][jr] * DN - dg1 - rm1) + EPSF));
    }
    qp0[mt] = o0; qp1[mt] = o1;
  }

  f32x4 av0[4], av1[4];
  #pragma unroll
  for (int dt = 0; dt < 4; ++dt) {
    av0[dt] = (f32x4){0.f, 0.f, 0.f, 0.f};
    av1[dt] = (f32x4){0.f, 0.f, 0.f, 0.f};
  }
  f32x4 aK0 = (f32x4){0.f, 0.f, 0.f, 0.f};
  f32x4 aK1 = (f32x4){0.f, 0.f, 0.f, 0.f};
  #pragma unroll
  for (int mt = 0; mt < 16; ++mt) {
    const short4v kcv = *(const short4v*)&kcf[mt * 256 + l * 4];
    aK0 = mfma16x16(qp0[mt], kcv, aK0);
    aK1 = mfma16x16(qp1[mt], kcv, aK1);
    #pragma unroll
    for (int dt = 0; dt < 4; ++dt) {
      const short4v ch = *(const short4v*)&ctf[((0 * 16 + mt) * 4 + dt) * 256 + l * 4];
      const short4v cl = *(const short4v*)&ctf[((16 + mt) * 4 + dt) * 256 + l * 4];
      av0[dt] = mfma16x16(qp0[mt], ch, av0[dt]);
      av0[dt] = mfma16x16(qp0[mt], cl, av0[dt]);
      av1[dt] = mfma16x16(qp1[mt], ch, av1[dt]);
      av1[dt] = mfma16x16(qp1[mt], cl, av1[dt]);
    }
  }

  float di0[4], di1[4];
  #pragma unroll
  for (int jr = 0; jr < 4; ++jr) {
    const float h0 = __shfl(aK0[jr], (l & 48), 64);
    const float l0 = __shfl(aK0[jr], (l & 48) | 1, 64);
    const float h1 = __shfl(aK1[jr], (l & 48), 64);
    const float l1 = __shfl(aK1[jr], (l & 48) | 1, 64);
    di0[jr] = 1.0f / (h0 + l0);
    di1[jr] = 1.0f / (h1 + l1);
  }

  #pragma unroll
  for (int dt = 0; dt < 4; ++dt)
    #pragma unroll
    for (int jr = 0; jr < 4; ++jr) {
      const int col = h * DHD + dt * 16 + ll;
      attb[(size_t)(rowb0 + lh * 4 + jr) * DM + col] = f2bf(av0[dt][jr] * di0[jr]);
      attb[(size_t)(rowb0 + 16 + lh * 4 + jr) * DM + col] = f2bf(av1[dt][jr] * di1[jr]);
    }
}

// ---------------------------------------------------------------------------
extern "C" void kernel_launch(void* const* d_in, const int* in_sizes, int n_in,
                              void* d_out, int out_size, void* d_ws, size_t ws_size,
                              hipStream_t stream)
{
  const float* x  = (const float*)d_in[0];
  const float* Wq = (const float*)d_in[1];
  const float* Wk = (const float*)d_in[2];
  const float* Wv = (const float*)d_in[3];
  const float* Wo = (const float*)d_in[4];
  const float* bo = (const float*)d_in[5];
  const float* P  = (const float*)d_in[6];
  float* out = (float*)d_out;

  char* wp = (char*)d_ws;
  ushort_t* QHL   = (ushort_t*)(wp + 0);            // 64 MB [row][h][128]
  ushort_t* KHL   = (ushort_t*)(wp + 67108864);     // 64 MB (ATTB overlays)
  ushort_t* VT    = (ushort_t*)(wp + 134217728);    // 32 MB [bh][dh][n]
  ushort_t* Wqt   = (ushort_t*)(wp + 167772160);    // 2 MB  } contiguous:
  ushort_t* Wkt   = (ushort_t*)(wp + 169869312);    // 2 MB  } Bt for the merged
  ushort_t* Wvt   = (ushort_t*)(wp + 171966464);    // 2 MB  } QKV GEMM (3072 rows)
  ushort_t* Wot   = (ushort_t*)(wp + 174063616);    // 2 MB
  ushort_t* PHI   = (ushort_t*)(wp + 176160768);
  ushort_t* PLO   = (ushort_t*)(wp + 176193536);
  float*    DIAGQ = (float*)(wp + 176226304);       // 1 MB
  float*    DIAGK = (float*)(wp + 177274880);       // 1 MB
  float*    PARTK = (float*)(wp + 178323456);       // 512 KB
  float*    MW    = (float*)(wp + 178847744);       // 8 KB
  float*    VSUM  = (float*)(wp + 178855936);       // 16 KB
  unsigned* MX    = (unsigned*)(wp + 178872320);    // 256 B
  float*    KCS   = (float*)(wp + 178872576);       // 64 KB
  ushort_t* CTH   = (ushort_t*)(wp + 178938112);    // 2 MB
  ushort_t* CTL   = (ushort_t*)(wp + 181035264);    // 2 MB -> end 183132416
  ushort_t* ATTB  = KHL;

  // scratch carved out of d_out (fully overwritten by the final Wo-GEMM):
  float*    PARTC = (float*)d_out;                           // 32 MB
  ushort_t* XB    = (ushort_t*)((char*)d_out + 33554432);    // 32 MB

  dim3 tg(16, 16);
  wtrans<<<tg, 256, 0, stream>>>(Wq, Wqt);
  wtrans<<<tg, 256, 0, stream>>>(Wk, Wkt);
  wtrans<<<tg, 256, 0, stream>>>(Wv, Wvt);
  wtrans<<<tg, 256, 0, stream>>>(Wo, Wot);
  psplit<<<64, 256, 0, stream>>>(P, PHI, PLO);
  xconv<<<8192, 256, 0, stream>>>(x, XB);
  hipMemsetAsync(VSUM, 0, 16384 + 256, stream);   // VSUM + MX

  gemm_qkv<<<3072, 256, 0, stream>>>(XB, Wqt, QHL, KHL, VT, DIAGQ, DIAGK);

  kside5<<<512, 256, 0, stream>>>(KHL, VT, PHI, PLO, DIAGK, PARTC, PARTK, MW, VSUM, MX);
  combine<<<256, 256, 0, stream>>>(PARTC, PARTK, MW, VSUM, MX, KCS, CTH, CTL);
  qside6<<<1024, 512, 139264, stream>>>(QHL, PHI, PLO, DIAGQ, KCS, CTH, CTL, ATTB);

  gemm_wo<<<1024, 256, 0, stream>>>(ATTB, Wot, bo, out);
}